// Round 1
// baseline (835.172 us; speedup 1.0000x reference)
//
#include <hip/hip_runtime.h>
#include <math.h>

#define N_NODES 100000
#define N_EDGES 1600000
#define F_DIM 128
#define C_DIM 40
#define SCAN_CHUNK 1024
#define NBLK_SCAN ((N_NODES + SCAN_CHUNK - 1) / SCAN_CHUNK)   // 98

// ---------------- CSR build ----------------

__global__ __launch_bounds__(256) void k_hist(const int* __restrict__ row, int* __restrict__ cnt) {
    int e = blockIdx.x * 256 + threadIdx.x;
    if (e < N_EDGES) atomicAdd(&cnt[row[e]], 1);
}

__global__ __launch_bounds__(256) void k_scan1(const int* __restrict__ cnt,
                                               int* __restrict__ off, int* __restrict__ blksum) {
    __shared__ int s[256];
    int t = threadIdx.x;
    int base = blockIdx.x * SCAN_CHUNK + t * 4;
    int v0 = (base + 0 < N_NODES) ? cnt[base + 0] : 0;
    int v1 = (base + 1 < N_NODES) ? cnt[base + 1] : 0;
    int v2 = (base + 2 < N_NODES) ? cnt[base + 2] : 0;
    int v3 = (base + 3 < N_NODES) ? cnt[base + 3] : 0;
    int s0 = v0, s1 = s0 + v1, s2 = s1 + v2, s3 = s2 + v3;
    s[t] = s3;
    __syncthreads();
    for (int d = 1; d < 256; d <<= 1) {
        int x = (t >= d) ? s[t - d] : 0;
        __syncthreads();
        s[t] += x;
        __syncthreads();
    }
    int excl = s[t] - s3;
    if (base + 0 < N_NODES) off[base + 0] = excl;
    if (base + 1 < N_NODES) off[base + 1] = excl + s0;
    if (base + 2 < N_NODES) off[base + 2] = excl + s1;
    if (base + 3 < N_NODES) off[base + 3] = excl + s2;
    if (t == 255) blksum[blockIdx.x] = s[255];
}

__global__ __launch_bounds__(256) void k_scan2(int* __restrict__ blksum) {
    __shared__ int s[256];
    int t = threadIdx.x;
    int v = (t < NBLK_SCAN) ? blksum[t] : 0;
    s[t] = v;
    __syncthreads();
    for (int d = 1; d < 256; d <<= 1) {
        int x = (t >= d) ? s[t - d] : 0;
        __syncthreads();
        s[t] += x;
        __syncthreads();
    }
    if (t < NBLK_SCAN) blksum[t] = s[t] - v;  // exclusive
}

__global__ __launch_bounds__(256) void k_scan3(const int* __restrict__ cnt, int* __restrict__ off,
                                               const int* __restrict__ blksum,
                                               int* __restrict__ fill, float* __restrict__ dinv) {
    int i = blockIdx.x * 256 + threadIdx.x;
    if (i < N_NODES) {
        int o = off[i] + blksum[i >> 10];
        off[i] = o;
        fill[i] = o;
        dinv[i] = rsqrtf((float)cnt[i] + 1.0f);   // GCN degree = in-row-count + self-loop
    }
}

__global__ __launch_bounds__(256) void k_scatter(const int* __restrict__ row, const int* __restrict__ col,
                                                 int* __restrict__ fill, int* __restrict__ scol) {
    int e = blockIdx.x * 256 + threadIdx.x;
    if (e < N_EDGES) {
        int r = row[e];
        int p = atomicAdd(&fill[r], 1);
        scol[p] = col[e];
    }
}

// ---------------- mask packing: 128 bool feats -> 2x u64 per node ----------------

__global__ __launch_bounds__(256) void k_maskpack(const int* __restrict__ mask,
                                                  unsigned long long* __restrict__ mbits) {
    int wid = (blockIdx.x * 256 + threadIdx.x) >> 6;
    int l = threadIdx.x & 63;
    if (wid >= N_NODES) return;
    int m0 = mask[wid * F_DIM + l];
    int m1 = mask[wid * F_DIM + 64 + l];
    unsigned long long b0 = __ballot(m0 != 0);
    unsigned long long b1 = __ballot(m1 != 0);
    if (l == 0) {
        mbits[wid * 2 + 0] = b0;
        mbits[wid * 2 + 1] = b1;
    }
}

// ---------------- PaGNN masked-mean aggregation: wave per node ----------------

__global__ __launch_bounds__(256) void k_agg(const float* __restrict__ x,
                                             const unsigned long long* __restrict__ mbits,
                                             const int* __restrict__ scol,
                                             const int* __restrict__ off, const int* __restrict__ cnt,
                                             float* __restrict__ hbuf) {
    int wid = (blockIdx.x * 256 + threadIdx.x) >> 6;
    int l = threadIdx.x & 63;
    if (wid >= N_NODES) return;
    int start = off[wid], len = cnt[wid];
    int f = 2 * l;                // this lane owns features f, f+1
    int wsel = l >> 5;            // which 64-bit word holds them
    int sh = (2 * l) & 63;
    float ax = 0.f, ay = 0.f, dx = 0.f, dy = 0.f;
    for (int j = 0; j < len; j++) {
        int c = scol[start + j];
        unsigned long long w = mbits[c * 2 + wsel];
        unsigned int pair = (unsigned int)(w >> sh) & 3u;
        float2 xv = *(const float2*)(x + c * F_DIM + f);
        float m0 = (float)(pair & 1u);
        float m1 = (float)(pair >> 1);
        ax += m0 * xv.x;
        ay += m1 * xv.y;
        dx += m0;
        dy += m1;
    }
    float2 hn;
    hn.x = ax / fmaxf(dx, 1.0f);
    hn.y = ay / fmaxf(dy, 1.0f);
    *(float2*)(hbuf + wid * F_DIM + f) = hn;
}

// ---------------- GEMM1: h = relu(hn @ W1 + b1), in-place on hbuf ----------------

#define G1R 16
__global__ __launch_bounds__(256) void k_gemm1(float* __restrict__ hbuf,
                                               const float* __restrict__ W1,
                                               const float* __restrict__ b1) {
    __shared__ float sW[128 * 128];   // 64 KB
    __shared__ float srow[G1R * 128]; // 8 KB
    __shared__ float sb[128];
    int t = threadIdx.x;
    int rowbase = blockIdx.x * G1R;
    for (int i = t; i < 4096; i += 256) ((float4*)sW)[i] = ((const float4*)W1)[i];
    if (t < 128) sb[t] = b1[t];
    for (int i = t; i < G1R * 128 / 4; i += 256)
        ((float4*)srow)[i] = ((const float4*)(hbuf + rowbase * F_DIM))[i];
    __syncthreads();

    int w = t >> 6, l = t & 63;
    int c4 = (l & 31) * 4;
    int rh = l >> 5;
    int r0 = w * 4 + rh * 2;  // local rows r0, r0+1
    const float* srA = &srow[r0 * 128];
    const float* srB = &srow[(r0 + 1) * 128];
    float4 acc0 = {0.f, 0.f, 0.f, 0.f}, acc1 = {0.f, 0.f, 0.f, 0.f};
#pragma unroll 4
    for (int k = 0; k < 128; k++) {
        float4 wv = *(const float4*)&sW[k * 128 + c4];
        float a0 = srA[k];
        float a1 = srB[k];
        acc0.x += a0 * wv.x; acc0.y += a0 * wv.y; acc0.z += a0 * wv.z; acc0.w += a0 * wv.w;
        acc1.x += a1 * wv.x; acc1.y += a1 * wv.y; acc1.z += a1 * wv.z; acc1.w += a1 * wv.w;
    }
    float4 bb = *(const float4*)&sb[c4];
    float4 o0, o1;
    o0.x = fmaxf(acc0.x + bb.x, 0.f); o0.y = fmaxf(acc0.y + bb.y, 0.f);
    o0.z = fmaxf(acc0.z + bb.z, 0.f); o0.w = fmaxf(acc0.w + bb.w, 0.f);
    o1.x = fmaxf(acc1.x + bb.x, 0.f); o1.y = fmaxf(acc1.y + bb.y, 0.f);
    o1.z = fmaxf(acc1.z + bb.z, 0.f); o1.w = fmaxf(acc1.w + bb.w, 0.f);
    int gr = rowbase + r0;
    *(float4*)&hbuf[gr * F_DIM + c4] = o0;
    *(float4*)&hbuf[(gr + 1) * F_DIM + c4] = o1;
}

// ---------------- GEMM2: xw = h @ W2  (cols padded 40->64 in LDS) ----------------

__global__ __launch_bounds__(256) void k_gemm2(const float* __restrict__ hbuf,
                                               const float* __restrict__ W2,
                                               float* __restrict__ xw) {
    __shared__ float sW2[128 * 64];   // 32 KB, cols >=40 are zero
    __shared__ float srow[32 * 128];  // 16 KB
    int t = threadIdx.x;
    int rowbase = blockIdx.x * 32;
    for (int i = t; i < 8192; i += 256) {
        int k = i >> 6, c = i & 63;
        sW2[i] = (c < C_DIM) ? W2[k * C_DIM + c] : 0.0f;
    }
    for (int i = t; i < 1024; i += 256)
        ((float4*)srow)[i] = ((const float4*)(hbuf + rowbase * F_DIM))[i];
    __syncthreads();

    int w = t >> 6, l = t & 63;
    const float* sr = &srow[w * 8 * 128];  // this wave's 8 rows
    float acc[8] = {0.f, 0.f, 0.f, 0.f, 0.f, 0.f, 0.f, 0.f};
    for (int k = 0; k < 128; k += 4) {
        float w0 = sW2[(k + 0) * 64 + l];
        float w1 = sW2[(k + 1) * 64 + l];
        float w2 = sW2[(k + 2) * 64 + l];
        float w3 = sW2[(k + 3) * 64 + l];
#pragma unroll
        for (int r = 0; r < 8; r++) {
            float4 a = *(const float4*)&sr[r * 128 + k];
            acc[r] += a.x * w0 + a.y * w1 + a.z * w2 + a.w * w3;
        }
    }
    if (l < C_DIM) {
        int grow = rowbase + w * 8;
#pragma unroll
        for (int r = 0; r < 8; r++) xw[(grow + r) * C_DIM + l] = acc[r];
    }
}

// ---------------- GCN conv + bias + log_softmax: wave per node ----------------

__global__ __launch_bounds__(256) void k_gcn(const float* __restrict__ xw,
                                             const float* __restrict__ dinv,
                                             const int* __restrict__ scol,
                                             const int* __restrict__ off, const int* __restrict__ cnt,
                                             const float* __restrict__ b2,
                                             float* __restrict__ out) {
    int wid = (blockIdx.x * 256 + threadIdx.x) >> 6;
    int l = threadIdx.x & 63;
    if (wid >= N_NODES) return;
    int start = off[wid], len = cnt[wid];
    float s = 0.0f;
    for (int j = 0; j < len; j++) {
        int c = scol[start + j];
        float dv = dinv[c];
        float v = (l < C_DIM) ? xw[c * C_DIM + l] : 0.0f;
        s += dv * v;
    }
    float di = dinv[wid];
    float val;
    if (l < C_DIM)
        val = di * s + di * di * xw[wid * C_DIM + l] + b2[l];
    else
        val = -1e30f;
    // wave-wide max
    float m = val;
#pragma unroll
    for (int o = 32; o > 0; o >>= 1) m = fmaxf(m, __shfl_xor(m, o, 64));
    float e = expf(val - m);
#pragma unroll
    for (int o = 32; o > 0; o >>= 1) e += __shfl_xor(e, o, 64);
    if (l < C_DIM) {
        float lse = m + logf(e);
        float v2 = di * s + di * di * xw[wid * C_DIM + l] + b2[l];
        out[wid * C_DIM + l] = v2 - lse;
    }
}

// ---------------- launch ----------------

extern "C" void kernel_launch(void* const* d_in, const int* in_sizes, int n_in,
                              void* d_out, int out_size, void* d_ws, size_t ws_size,
                              hipStream_t stream) {
    const float* x = (const float*)d_in[0];
    const int* mask = (const int*)d_in[1];
    const int* eidx = (const int*)d_in[2];
    const float* W1 = (const float*)d_in[3];
    const float* b1 = (const float*)d_in[4];
    const float* W2 = (const float*)d_in[5];
    const float* b2 = (const float*)d_in[6];
    float* out = (float*)d_out;

    const int* row = eidx;
    const int* col = eidx + N_EDGES;

    // workspace layout (256B aligned regions)
    char* base = (char*)d_ws;
    size_t o = 0;
    auto alloc = [&](size_t bytes) {
        void* p = base + o;
        o = (o + bytes + 255) & ~(size_t)255;
        return p;
    };
    int* cnt = (int*)alloc(N_NODES * 4);
    int* off = (int*)alloc(N_NODES * 4);
    int* fill = (int*)alloc(N_NODES * 4);
    float* dinv = (float*)alloc(N_NODES * 4);
    int* blksum = (int*)alloc(256 * 4);
    unsigned long long* mbits = (unsigned long long*)alloc(N_NODES * 16);
    int* scol = (int*)alloc(N_EDGES * 4);
    float* hbuf = (float*)alloc((size_t)N_NODES * F_DIM * 4);
    float* xw = (float*)alloc((size_t)N_NODES * C_DIM * 4);
    (void)ws_size;

    hipMemsetAsync(cnt, 0, N_NODES * 4, stream);

    int gE = (N_EDGES + 255) / 256;                 // 6250
    int gN = (N_NODES + 255) / 256;                 // 391
    int gWave = (N_NODES * 64 + 255) / 256;         // 25000

    k_hist<<<gE, 256, 0, stream>>>(row, cnt);
    k_scan1<<<NBLK_SCAN, 256, 0, stream>>>(cnt, off, blksum);
    k_scan2<<<1, 256, 0, stream>>>(blksum);
    k_scan3<<<gN, 256, 0, stream>>>(cnt, off, blksum, fill, dinv);
    k_scatter<<<gE, 256, 0, stream>>>(row, col, fill, scol);
    k_maskpack<<<gWave, 256, 0, stream>>>(mask, mbits);
    k_agg<<<gWave, 256, 0, stream>>>(x, mbits, scol, off, cnt, hbuf);
    k_gemm1<<<N_NODES / G1R, 256, 0, stream>>>(hbuf, W1, b1);
    k_gemm2<<<N_NODES / 32, 256, 0, stream>>>(hbuf, W2, xw);
    k_gcn<<<gWave, 256, 0, stream>>>(xw, dinv, scol, off, cnt, b2, out);
}

// Round 2
// 672.425 us; speedup vs baseline: 1.2420x; 1.2420x over previous
//
#include <hip/hip_runtime.h>
#include <math.h>

#define N_NODES 100000
#define N_EDGES 1600000
#define F_DIM 128
#define C_DIM 40
#define SCAN_CHUNK 1024
#define NBLK_SCAN ((N_NODES + SCAN_CHUNK - 1) / SCAN_CHUNK)   // 98

// ---------------- CSR build ----------------

__global__ __launch_bounds__(256) void k_hist(const int* __restrict__ row, int* __restrict__ cnt) {
    int e = blockIdx.x * 256 + threadIdx.x;
    if (e < N_EDGES) atomicAdd(&cnt[row[e]], 1);
}

__global__ __launch_bounds__(256) void k_scan1(const int* __restrict__ cnt,
                                               int* __restrict__ off, int* __restrict__ blksum) {
    __shared__ int s[256];
    int t = threadIdx.x;
    int base = blockIdx.x * SCAN_CHUNK + t * 4;
    int v0 = (base + 0 < N_NODES) ? cnt[base + 0] : 0;
    int v1 = (base + 1 < N_NODES) ? cnt[base + 1] : 0;
    int v2 = (base + 2 < N_NODES) ? cnt[base + 2] : 0;
    int v3 = (base + 3 < N_NODES) ? cnt[base + 3] : 0;
    int s0 = v0, s1 = s0 + v1, s2 = s1 + v2, s3 = s2 + v3;
    s[t] = s3;
    __syncthreads();
    for (int d = 1; d < 256; d <<= 1) {
        int x = (t >= d) ? s[t - d] : 0;
        __syncthreads();
        s[t] += x;
        __syncthreads();
    }
    int excl = s[t] - s3;
    if (base + 0 < N_NODES) off[base + 0] = excl;
    if (base + 1 < N_NODES) off[base + 1] = excl + s0;
    if (base + 2 < N_NODES) off[base + 2] = excl + s1;
    if (base + 3 < N_NODES) off[base + 3] = excl + s2;
    if (t == 255) blksum[blockIdx.x] = s[255];
}

__global__ __launch_bounds__(256) void k_scan2(int* __restrict__ blksum) {
    __shared__ int s[256];
    int t = threadIdx.x;
    int v = (t < NBLK_SCAN) ? blksum[t] : 0;
    s[t] = v;
    __syncthreads();
    for (int d = 1; d < 256; d <<= 1) {
        int x = (t >= d) ? s[t - d] : 0;
        __syncthreads();
        s[t] += x;
        __syncthreads();
    }
    if (t < NBLK_SCAN) blksum[t] = s[t] - v;  // exclusive
}

__global__ __launch_bounds__(256) void k_scan3(const int* __restrict__ cnt, int* __restrict__ off,
                                               const int* __restrict__ blksum,
                                               int* __restrict__ fill, float* __restrict__ dinv) {
    int i = blockIdx.x * 256 + threadIdx.x;
    if (i < N_NODES) {
        int o = off[i] + blksum[i >> 10];
        off[i] = o;
        fill[i] = o;
        dinv[i] = rsqrtf((float)cnt[i] + 1.0f);   // GCN degree = in-row-count + self-loop
    }
}

__global__ __launch_bounds__(256) void k_scatter(const int* __restrict__ row, const int* __restrict__ col,
                                                 int* __restrict__ fill, int* __restrict__ scol) {
    int e = blockIdx.x * 256 + threadIdx.x;
    if (e < N_EDGES) {
        int r = row[e];
        int p = atomicAdd(&fill[r], 1);
        scol[p] = col[e];
    }
}

// ---------------- mask packing: 128 bool feats -> 2x u64 per node ----------------

__global__ __launch_bounds__(256) void k_maskpack(const int* __restrict__ mask,
                                                  unsigned long long* __restrict__ mbits) {
    int wid = (blockIdx.x * 256 + threadIdx.x) >> 6;
    int l = threadIdx.x & 63;
    if (wid >= N_NODES) return;
    int m0 = mask[wid * F_DIM + l];
    int m1 = mask[wid * F_DIM + 64 + l];
    unsigned long long b0 = __ballot(m0 != 0);
    unsigned long long b1 = __ballot(m1 != 0);
    if (l == 0) {
        mbits[wid * 2 + 0] = b0;
        mbits[wid * 2 + 1] = b1;
    }
}

// ---------------- PaGNN masked-mean aggregation: wave per node, unroll x4 ----------------

__global__ __launch_bounds__(256) void k_agg(const float* __restrict__ x,
                                             const unsigned long long* __restrict__ mbits,
                                             const int* __restrict__ scol,
                                             const int* __restrict__ off, const int* __restrict__ cnt,
                                             float* __restrict__ hbuf) {
    int wid = (blockIdx.x * 256 + threadIdx.x) >> 6;
    int l = threadIdx.x & 63;
    if (wid >= N_NODES) return;
    int start = off[wid], len = cnt[wid];
    int f = 2 * l;                // this lane owns features f, f+1
    int wsel = l >> 5;            // which 64-bit word holds them
    int sh = f & 63;

    // preload up to 64 neighbor ids into lane registers (1 coalesced load)
    int n = len < 64 ? len : 64;
    int myc = (l < n) ? scol[start + l] : 0;

    float ax0 = 0.f, ay0 = 0.f, dx0 = 0.f, dy0 = 0.f;
    float ax1 = 0.f, ay1 = 0.f, dx1 = 0.f, dy1 = 0.f;
    float ax2 = 0.f, ay2 = 0.f, dx2 = 0.f, dy2 = 0.f;
    float ax3 = 0.f, ay3 = 0.f, dx3 = 0.f, dy3 = 0.f;

    int j = 0;
    for (; j + 4 <= n; j += 4) {
        int c0 = __shfl(myc, j,     64);
        int c1 = __shfl(myc, j + 1, 64);
        int c2 = __shfl(myc, j + 2, 64);
        int c3 = __shfl(myc, j + 3, 64);
        unsigned long long w0 = mbits[c0 * 2 + wsel];
        unsigned long long w1 = mbits[c1 * 2 + wsel];
        unsigned long long w2 = mbits[c2 * 2 + wsel];
        unsigned long long w3 = mbits[c3 * 2 + wsel];
        float2 v0 = *(const float2*)(x + c0 * F_DIM + f);
        float2 v1 = *(const float2*)(x + c1 * F_DIM + f);
        float2 v2 = *(const float2*)(x + c2 * F_DIM + f);
        float2 v3 = *(const float2*)(x + c3 * F_DIM + f);
        float m;
        m = (float)((w0 >> sh) & 1ull);       ax0 += m * v0.x; dx0 += m;
        m = (float)((w0 >> (sh + 1)) & 1ull); ay0 += m * v0.y; dy0 += m;
        m = (float)((w1 >> sh) & 1ull);       ax1 += m * v1.x; dx1 += m;
        m = (float)((w1 >> (sh + 1)) & 1ull); ay1 += m * v1.y; dy1 += m;
        m = (float)((w2 >> sh) & 1ull);       ax2 += m * v2.x; dx2 += m;
        m = (float)((w2 >> (sh + 1)) & 1ull); ay2 += m * v2.y; dy2 += m;
        m = (float)((w3 >> sh) & 1ull);       ax3 += m * v3.x; dx3 += m;
        m = (float)((w3 >> (sh + 1)) & 1ull); ay3 += m * v3.y; dy3 += m;
    }
    for (; j < n; j++) {
        int c = __shfl(myc, j, 64);
        unsigned long long w = mbits[c * 2 + wsel];
        float2 v = *(const float2*)(x + c * F_DIM + f);
        float m;
        m = (float)((w >> sh) & 1ull);       ax0 += m * v.x; dx0 += m;
        m = (float)((w >> (sh + 1)) & 1ull); ay0 += m * v.y; dy0 += m;
    }
    for (int j2 = 64; j2 < len; j2++) {   // rare tail (degree > 64)
        int c = scol[start + j2];
        unsigned long long w = mbits[c * 2 + wsel];
        float2 v = *(const float2*)(x + c * F_DIM + f);
        float m;
        m = (float)((w >> sh) & 1ull);       ax0 += m * v.x; dx0 += m;
        m = (float)((w >> (sh + 1)) & 1ull); ay0 += m * v.y; dy0 += m;
    }

    float ax = (ax0 + ax1) + (ax2 + ax3);
    float ay = (ay0 + ay1) + (ay2 + ay3);
    float dx = (dx0 + dx1) + (dx2 + dx3);
    float dy = (dy0 + dy1) + (dy2 + dy3);
    float2 hn;
    hn.x = ax / fmaxf(dx, 1.0f);
    hn.y = ay / fmaxf(dy, 1.0f);
    *(float2*)(hbuf + wid * F_DIM + f) = hn;
}

// ---------------- GEMM1: h = relu(hn @ W1 + b1), in-place on hbuf ----------------

#define G1R 16
__global__ __launch_bounds__(256) void k_gemm1(float* __restrict__ hbuf,
                                               const float* __restrict__ W1,
                                               const float* __restrict__ b1) {
    __shared__ float sW[128 * 128];   // 64 KB
    __shared__ float srow[G1R * 128]; // 8 KB
    __shared__ float sb[128];
    int t = threadIdx.x;
    int rowbase = blockIdx.x * G1R;
    for (int i = t; i < 4096; i += 256) ((float4*)sW)[i] = ((const float4*)W1)[i];
    if (t < 128) sb[t] = b1[t];
    for (int i = t; i < G1R * 128 / 4; i += 256)
        ((float4*)srow)[i] = ((const float4*)(hbuf + rowbase * F_DIM))[i];
    __syncthreads();

    int w = t >> 6, l = t & 63;
    int c4 = (l & 31) * 4;
    int rh = l >> 5;
    int r0 = w * 4 + rh * 2;  // local rows r0, r0+1
    const float* srA = &srow[r0 * 128];
    const float* srB = &srow[(r0 + 1) * 128];
    float4 acc0 = {0.f, 0.f, 0.f, 0.f}, acc1 = {0.f, 0.f, 0.f, 0.f};
#pragma unroll 4
    for (int k = 0; k < 128; k++) {
        float4 wv = *(const float4*)&sW[k * 128 + c4];
        float a0 = srA[k];
        float a1 = srB[k];
        acc0.x += a0 * wv.x; acc0.y += a0 * wv.y; acc0.z += a0 * wv.z; acc0.w += a0 * wv.w;
        acc1.x += a1 * wv.x; acc1.y += a1 * wv.y; acc1.z += a1 * wv.z; acc1.w += a1 * wv.w;
    }
    float4 bb = *(const float4*)&sb[c4];
    float4 o0, o1;
    o0.x = fmaxf(acc0.x + bb.x, 0.f); o0.y = fmaxf(acc0.y + bb.y, 0.f);
    o0.z = fmaxf(acc0.z + bb.z, 0.f); o0.w = fmaxf(acc0.w + bb.w, 0.f);
    o1.x = fmaxf(acc1.x + bb.x, 0.f); o1.y = fmaxf(acc1.y + bb.y, 0.f);
    o1.z = fmaxf(acc1.z + bb.z, 0.f); o1.w = fmaxf(acc1.w + bb.w, 0.f);
    int gr = rowbase + r0;
    *(float4*)&hbuf[gr * F_DIM + c4] = o0;
    *(float4*)&hbuf[(gr + 1) * F_DIM + c4] = o1;
}

// ---------------- GEMM2: xws = dinv * (h @ W2)  (cols padded 40->64 in LDS) ----------------

__global__ __launch_bounds__(256) void k_gemm2(const float* __restrict__ hbuf,
                                               const float* __restrict__ W2,
                                               const float* __restrict__ dinv,
                                               float* __restrict__ xws) {
    __shared__ float sW2[128 * 64];   // 32 KB, cols >=40 are zero
    __shared__ float srow[32 * 128];  // 16 KB
    int t = threadIdx.x;
    int rowbase = blockIdx.x * 32;
    for (int i = t; i < 8192; i += 256) {
        int k = i >> 6, c = i & 63;
        sW2[i] = (c < C_DIM) ? W2[k * C_DIM + c] : 0.0f;
    }
    for (int i = t; i < 1024; i += 256)
        ((float4*)srow)[i] = ((const float4*)(hbuf + rowbase * F_DIM))[i];
    __syncthreads();

    int w = t >> 6, l = t & 63;
    const float* sr = &srow[w * 8 * 128];  // this wave's 8 rows
    float acc[8] = {0.f, 0.f, 0.f, 0.f, 0.f, 0.f, 0.f, 0.f};
    for (int k = 0; k < 128; k += 4) {
        float w0 = sW2[(k + 0) * 64 + l];
        float w1 = sW2[(k + 1) * 64 + l];
        float w2 = sW2[(k + 2) * 64 + l];
        float w3 = sW2[(k + 3) * 64 + l];
#pragma unroll
        for (int r = 0; r < 8; r++) {
            float4 a = *(const float4*)&sr[r * 128 + k];
            acc[r] += a.x * w0 + a.y * w1 + a.z * w2 + a.w * w3;
        }
    }
    if (l < C_DIM) {
        int grow = rowbase + w * 8;
#pragma unroll
        for (int r = 0; r < 8; r++) xws[(grow + r) * C_DIM + l] = acc[r] * dinv[grow + r];
    }
}

// ---------------- GCN conv + bias + log_softmax: wave per node, unroll x4 ----------------
// xws is already dinv-prescaled: out_c = di*(sum_nbr xws[c] + xws[self]) + b2

__global__ __launch_bounds__(256) void k_gcn(const float* __restrict__ xws,
                                             const float* __restrict__ dinv,
                                             const int* __restrict__ scol,
                                             const int* __restrict__ off, const int* __restrict__ cnt,
                                             const float* __restrict__ b2,
                                             float* __restrict__ out) {
    int wid = (blockIdx.x * 256 + threadIdx.x) >> 6;
    int l = threadIdx.x & 63;
    if (wid >= N_NODES) return;
    int start = off[wid], len = cnt[wid];
    bool act = l < C_DIM;
    int lc = act ? l : 0;

    int n = len < 64 ? len : 64;
    int myc = (l < n) ? scol[start + l] : 0;

    float s0 = 0.f, s1 = 0.f, s2 = 0.f, s3 = 0.f;
    int j = 0;
    for (; j + 4 <= n; j += 4) {
        int c0 = __shfl(myc, j,     64);
        int c1 = __shfl(myc, j + 1, 64);
        int c2 = __shfl(myc, j + 2, 64);
        int c3 = __shfl(myc, j + 3, 64);
        s0 += xws[c0 * C_DIM + lc];
        s1 += xws[c1 * C_DIM + lc];
        s2 += xws[c2 * C_DIM + lc];
        s3 += xws[c3 * C_DIM + lc];
    }
    for (; j < n; j++) {
        int c = __shfl(myc, j, 64);
        s0 += xws[c * C_DIM + lc];
    }
    for (int j2 = 64; j2 < len; j2++) {
        s0 += xws[scol[start + j2] * C_DIM + lc];
    }

    float di = dinv[wid];
    float s = (s0 + s1) + (s2 + s3) + xws[wid * C_DIM + lc];
    float val = act ? (di * s + b2[lc]) : -1e30f;

    float m = val;
#pragma unroll
    for (int o = 32; o > 0; o >>= 1) m = fmaxf(m, __shfl_xor(m, o, 64));
    float e = __expf(val - m);
#pragma unroll
    for (int o = 32; o > 0; o >>= 1) e += __shfl_xor(e, o, 64);
    if (act) {
        float lse = m + __logf(e);
        out[wid * C_DIM + l] = val - lse;
    }
}

// ---------------- launch ----------------

extern "C" void kernel_launch(void* const* d_in, const int* in_sizes, int n_in,
                              void* d_out, int out_size, void* d_ws, size_t ws_size,
                              hipStream_t stream) {
    const float* x = (const float*)d_in[0];
    const int* mask = (const int*)d_in[1];
    const int* eidx = (const int*)d_in[2];
    const float* W1 = (const float*)d_in[3];
    const float* b1 = (const float*)d_in[4];
    const float* W2 = (const float*)d_in[5];
    const float* b2 = (const float*)d_in[6];
    float* out = (float*)d_out;

    const int* row = eidx;
    const int* col = eidx + N_EDGES;

    // workspace layout (256B aligned regions)
    char* base = (char*)d_ws;
    size_t o = 0;
    auto alloc = [&](size_t bytes) {
        void* p = base + o;
        o = (o + bytes + 255) & ~(size_t)255;
        return p;
    };
    int* cnt = (int*)alloc(N_NODES * 4);
    int* off = (int*)alloc(N_NODES * 4);
    int* fill = (int*)alloc(N_NODES * 4);
    float* dinv = (float*)alloc(N_NODES * 4);
    int* blksum = (int*)alloc(256 * 4);
    unsigned long long* mbits = (unsigned long long*)alloc(N_NODES * 16);
    int* scol = (int*)alloc(N_EDGES * 4);
    float* hbuf = (float*)alloc((size_t)N_NODES * F_DIM * 4);
    float* xws = (float*)alloc((size_t)N_NODES * C_DIM * 4);
    (void)ws_size;

    hipMemsetAsync(cnt, 0, N_NODES * 4, stream);

    int gE = (N_EDGES + 255) / 256;                 // 6250
    int gN = (N_NODES + 255) / 256;                 // 391
    int gWave = (N_NODES * 64 + 255) / 256;         // 25000

    k_hist<<<gE, 256, 0, stream>>>(row, cnt);
    k_scan1<<<NBLK_SCAN, 256, 0, stream>>>(cnt, off, blksum);
    k_scan2<<<1, 256, 0, stream>>>(blksum);
    k_scan3<<<gN, 256, 0, stream>>>(cnt, off, blksum, fill, dinv);
    k_scatter<<<gE, 256, 0, stream>>>(row, col, fill, scol);
    k_maskpack<<<gWave, 256, 0, stream>>>(mask, mbits);
    k_agg<<<gWave, 256, 0, stream>>>(x, mbits, scol, off, cnt, hbuf);
    k_gemm1<<<N_NODES / G1R, 256, 0, stream>>>(hbuf, W1, b1);
    k_gemm2<<<N_NODES / 32, 256, 0, stream>>>(hbuf, W2, dinv, xws);
    k_gcn<<<gWave, 256, 0, stream>>>(xws, dinv, scol, off, cnt, b2, out);
}

// Round 3
// 618.492 us; speedup vs baseline: 1.3503x; 1.0872x over previous
//
#include <hip/hip_runtime.h>
#include <math.h>

#define N_NODES 100000
#define N_EDGES 1600000
#define F_DIM 128
#define C_DIM 40
#define SCAN_CHUNK 1024
#define NBLK_SCAN ((N_NODES + SCAN_CHUNK - 1) / SCAN_CHUNK)   // 98

typedef unsigned long long ull;

// ---------------- CSR build ----------------

__global__ __launch_bounds__(256) void k_hist(const int* __restrict__ row, int* __restrict__ cnt) {
    int e = blockIdx.x * 256 + threadIdx.x;
    if (e < N_EDGES) atomicAdd(&cnt[row[e]], 1);
}

__global__ __launch_bounds__(256) void k_scan1(const int* __restrict__ cnt,
                                               int* __restrict__ off, int* __restrict__ blksum) {
    __shared__ int s[256];
    int t = threadIdx.x;
    int base = blockIdx.x * SCAN_CHUNK + t * 4;
    int v0 = (base + 0 < N_NODES) ? cnt[base + 0] : 0;
    int v1 = (base + 1 < N_NODES) ? cnt[base + 1] : 0;
    int v2 = (base + 2 < N_NODES) ? cnt[base + 2] : 0;
    int v3 = (base + 3 < N_NODES) ? cnt[base + 3] : 0;
    int s0 = v0, s1 = s0 + v1, s2 = s1 + v2, s3 = s2 + v3;
    s[t] = s3;
    __syncthreads();
    for (int d = 1; d < 256; d <<= 1) {
        int x = (t >= d) ? s[t - d] : 0;
        __syncthreads();
        s[t] += x;
        __syncthreads();
    }
    int excl = s[t] - s3;
    if (base + 0 < N_NODES) off[base + 0] = excl;
    if (base + 1 < N_NODES) off[base + 1] = excl + s0;
    if (base + 2 < N_NODES) off[base + 2] = excl + s1;
    if (base + 3 < N_NODES) off[base + 3] = excl + s2;
    if (t == 255) blksum[blockIdx.x] = s[255];
}

__global__ __launch_bounds__(256) void k_scan2(int* __restrict__ blksum) {
    __shared__ int s[256];
    int t = threadIdx.x;
    int v = (t < NBLK_SCAN) ? blksum[t] : 0;
    s[t] = v;
    __syncthreads();
    for (int d = 1; d < 256; d <<= 1) {
        int x = (t >= d) ? s[t - d] : 0;
        __syncthreads();
        s[t] += x;
        __syncthreads();
    }
    if (t < NBLK_SCAN) blksum[t] = s[t] - v;  // exclusive
}

__global__ __launch_bounds__(256) void k_scan3(const int* __restrict__ cnt, int* __restrict__ off,
                                               const int* __restrict__ blksum,
                                               int* __restrict__ fill, float* __restrict__ dinv) {
    int i = blockIdx.x * 256 + threadIdx.x;
    if (i < N_NODES) {
        int o = off[i] + blksum[i >> 10];
        off[i] = o;
        fill[i] = o;
        dinv[i] = rsqrtf((float)cnt[i] + 1.0f);   // GCN degree = in-row-count + self-loop
    }
}

__global__ __launch_bounds__(256) void k_scatter(const int* __restrict__ row, const int* __restrict__ col,
                                                 int* __restrict__ fill, int* __restrict__ scol) {
    int e = blockIdx.x * 256 + threadIdx.x;
    if (e < N_EDGES) {
        int r = row[e];
        int p = atomicAdd(&fill[r], 1);
        scol[p] = col[e];
    }
}

// ---------------- mask packing: 128 bool feats -> 2x u64 per node ----------------

__global__ __launch_bounds__(256) void k_maskpack(const int* __restrict__ mask,
                                                  ull* __restrict__ mbits) {
    int wid = (blockIdx.x * 256 + threadIdx.x) >> 6;
    int l = threadIdx.x & 63;
    if (wid >= N_NODES) return;
    int m0 = mask[wid * F_DIM + l];
    int m1 = mask[wid * F_DIM + 64 + l];
    ull b0 = __ballot(m0 != 0);
    ull b1 = __ballot(m1 != 0);
    if (l == 0) {
        mbits[wid * 2 + 0] = b0;
        mbits[wid * 2 + 1] = b1;
    }
}

// ---------------- PaGNN masked-mean aggregation: wave/node, LDS ids, unroll 8 ----------------

#define AGG_EDGE(W, V, AX, AY, DX, DY)                       \
    {                                                        \
        unsigned int p = (unsigned int)((W) >> sh) & 3u;     \
        float m0 = (float)(p & 1u);                          \
        float m1 = (float)(p >> 1);                          \
        AX += m0 * (V).x; DX += m0;                          \
        AY += m1 * (V).y; DY += m1;                          \
    }

__global__ __launch_bounds__(256) void k_agg(const float* __restrict__ x,
                                             const ull* __restrict__ mbits,
                                             const int* __restrict__ scol,
                                             const int* __restrict__ off, const int* __restrict__ cnt,
                                             float* __restrict__ hbuf) {
    __shared__ int sids[4][64];
    int wv = threadIdx.x >> 6;
    int wid = blockIdx.x * 4 + wv;
    int l = threadIdx.x & 63;
    if (wid >= N_NODES) return;
    int start = off[wid], len = cnt[wid];
    int f = 2 * l;                // this lane owns features f, f+1
    int wsel = l >> 5;
    int sh = f & 63;

    int n = len < 64 ? len : 64;
    sids[wv][l] = (l < n) ? scol[start + l] : 0;   // same-wave write->read, lgkmcnt-ordered

    float ax0 = 0.f, ay0 = 0.f, dx0 = 0.f, dy0 = 0.f;
    float ax1 = 0.f, ay1 = 0.f, dx1 = 0.f, dy1 = 0.f;
    float ax2 = 0.f, ay2 = 0.f, dx2 = 0.f, dy2 = 0.f;
    float ax3 = 0.f, ay3 = 0.f, dx3 = 0.f, dy3 = 0.f;

    int j = 0;
    for (; j + 8 <= n; j += 8) {
        int4 ca = *(const int4*)&sids[wv][j];       // ds_read_b128: 4 ids at once
        int4 cb = *(const int4*)&sids[wv][j + 4];
        ull w0 = mbits[ca.x * 2 + wsel];
        ull w1 = mbits[ca.y * 2 + wsel];
        ull w2 = mbits[ca.z * 2 + wsel];
        ull w3 = mbits[ca.w * 2 + wsel];
        ull w4 = mbits[cb.x * 2 + wsel];
        ull w5 = mbits[cb.y * 2 + wsel];
        ull w6 = mbits[cb.z * 2 + wsel];
        ull w7 = mbits[cb.w * 2 + wsel];
        float2 v0 = *(const float2*)(x + ca.x * F_DIM + f);
        float2 v1 = *(const float2*)(x + ca.y * F_DIM + f);
        float2 v2 = *(const float2*)(x + ca.z * F_DIM + f);
        float2 v3 = *(const float2*)(x + ca.w * F_DIM + f);
        float2 v4 = *(const float2*)(x + cb.x * F_DIM + f);
        float2 v5 = *(const float2*)(x + cb.y * F_DIM + f);
        float2 v6 = *(const float2*)(x + cb.z * F_DIM + f);
        float2 v7 = *(const float2*)(x + cb.w * F_DIM + f);
        AGG_EDGE(w0, v0, ax0, ay0, dx0, dy0)
        AGG_EDGE(w1, v1, ax1, ay1, dx1, dy1)
        AGG_EDGE(w2, v2, ax2, ay2, dx2, dy2)
        AGG_EDGE(w3, v3, ax3, ay3, dx3, dy3)
        AGG_EDGE(w4, v4, ax0, ay0, dx0, dy0)
        AGG_EDGE(w5, v5, ax1, ay1, dx1, dy1)
        AGG_EDGE(w6, v6, ax2, ay2, dx2, dy2)
        AGG_EDGE(w7, v7, ax3, ay3, dx3, dy3)
    }
    for (; j + 4 <= n; j += 4) {
        int4 ca = *(const int4*)&sids[wv][j];
        ull w0 = mbits[ca.x * 2 + wsel];
        ull w1 = mbits[ca.y * 2 + wsel];
        ull w2 = mbits[ca.z * 2 + wsel];
        ull w3 = mbits[ca.w * 2 + wsel];
        float2 v0 = *(const float2*)(x + ca.x * F_DIM + f);
        float2 v1 = *(const float2*)(x + ca.y * F_DIM + f);
        float2 v2 = *(const float2*)(x + ca.z * F_DIM + f);
        float2 v3 = *(const float2*)(x + ca.w * F_DIM + f);
        AGG_EDGE(w0, v0, ax0, ay0, dx0, dy0)
        AGG_EDGE(w1, v1, ax1, ay1, dx1, dy1)
        AGG_EDGE(w2, v2, ax2, ay2, dx2, dy2)
        AGG_EDGE(w3, v3, ax3, ay3, dx3, dy3)
    }
    for (; j < n; j++) {
        int c = sids[wv][j];
        ull w = mbits[c * 2 + wsel];
        float2 v = *(const float2*)(x + c * F_DIM + f);
        AGG_EDGE(w, v, ax0, ay0, dx0, dy0)
    }
    for (int j2 = 64; j2 < len; j2++) {   // rare tail (degree > 64)
        int c = scol[start + j2];
        ull w = mbits[c * 2 + wsel];
        float2 v = *(const float2*)(x + c * F_DIM + f);
        AGG_EDGE(w, v, ax0, ay0, dx0, dy0)
    }

    float ax = (ax0 + ax1) + (ax2 + ax3);
    float ay = (ay0 + ay1) + (ay2 + ay3);
    float dx = (dx0 + dx1) + (dx2 + dx3);
    float dy = (dy0 + dy1) + (dy2 + dy3);
    float2 hn;
    hn.x = ax / fmaxf(dx, 1.0f);
    hn.y = ay / fmaxf(dy, 1.0f);
    *(float2*)(hbuf + wid * F_DIM + f) = hn;
}

// ---------------- GEMM1 (persistent): h = relu(hn @ W1 + b1), in-place ----------------

#define G1R 16
#define G1_TILES (N_NODES / G1R)   // 6250
#define G1_GRID 512

__global__ __launch_bounds__(256) void k_gemm1(float* __restrict__ hbuf,
                                               const float* __restrict__ W1,
                                               const float* __restrict__ b1) {
    __shared__ float sW[128 * 128];   // 64 KB, staged ONCE
    __shared__ float srow[G1R * 128]; // 8 KB
    __shared__ float sb[128];
    int t = threadIdx.x;
    for (int i = t; i < 4096; i += 256) ((float4*)sW)[i] = ((const float4*)W1)[i];
    if (t < 128) sb[t] = b1[t];

    int w = t >> 6, l = t & 63;
    int c4 = (l & 31) * 4;
    int rh = l >> 5;
    int r0 = w * 4 + rh * 2;
    const float* srA = &srow[r0 * 128];
    const float* srB = &srow[(r0 + 1) * 128];

    for (int tile = blockIdx.x; tile < G1_TILES; tile += G1_GRID) {
        int rowbase = tile * G1R;
        __syncthreads();   // protect srow from previous iter's readers
        for (int i = t; i < G1R * 128 / 4; i += 256)
            ((float4*)srow)[i] = ((const float4*)(hbuf + rowbase * F_DIM))[i];
        __syncthreads();

        float4 acc0 = {0.f, 0.f, 0.f, 0.f}, acc1 = {0.f, 0.f, 0.f, 0.f};
#pragma unroll 4
        for (int k = 0; k < 128; k++) {
            float4 wv2 = *(const float4*)&sW[k * 128 + c4];
            float a0 = srA[k];
            float a1 = srB[k];
            acc0.x += a0 * wv2.x; acc0.y += a0 * wv2.y; acc0.z += a0 * wv2.z; acc0.w += a0 * wv2.w;
            acc1.x += a1 * wv2.x; acc1.y += a1 * wv2.y; acc1.z += a1 * wv2.z; acc1.w += a1 * wv2.w;
        }
        float4 bb = *(const float4*)&sb[c4];
        float4 o0, o1;
        o0.x = fmaxf(acc0.x + bb.x, 0.f); o0.y = fmaxf(acc0.y + bb.y, 0.f);
        o0.z = fmaxf(acc0.z + bb.z, 0.f); o0.w = fmaxf(acc0.w + bb.w, 0.f);
        o1.x = fmaxf(acc1.x + bb.x, 0.f); o1.y = fmaxf(acc1.y + bb.y, 0.f);
        o1.z = fmaxf(acc1.z + bb.z, 0.f); o1.w = fmaxf(acc1.w + bb.w, 0.f);
        int gr = rowbase + r0;
        *(float4*)&hbuf[gr * F_DIM + c4] = o0;
        *(float4*)&hbuf[(gr + 1) * F_DIM + c4] = o1;
    }
}

// ---------------- GEMM2 (persistent): xws = dinv * (h @ W2), cols padded 40->64 ----------------

#define G2R 32
#define G2_TILES (N_NODES / G2R)   // 3125
#define G2_GRID 512

__global__ __launch_bounds__(256) void k_gemm2(const float* __restrict__ hbuf,
                                               const float* __restrict__ W2,
                                               const float* __restrict__ dinv,
                                               float* __restrict__ xws) {
    __shared__ float sW2[128 * 64];   // 32 KB, cols >=40 zero, staged ONCE
    __shared__ float srow[G2R * 128]; // 16 KB
    int t = threadIdx.x;
    for (int i = t; i < 8192; i += 256) {
        int k = i >> 6, c = i & 63;
        sW2[i] = (c < C_DIM) ? W2[k * C_DIM + c] : 0.0f;
    }
    int w = t >> 6, l = t & 63;
    const float* sr = &srow[w * 8 * 128];

    for (int tile = blockIdx.x; tile < G2_TILES; tile += G2_GRID) {
        int rowbase = tile * G2R;
        __syncthreads();
        for (int i = t; i < 1024; i += 256)
            ((float4*)srow)[i] = ((const float4*)(hbuf + rowbase * F_DIM))[i];
        __syncthreads();

        float acc[8] = {0.f, 0.f, 0.f, 0.f, 0.f, 0.f, 0.f, 0.f};
        for (int k = 0; k < 128; k += 4) {
            float w0 = sW2[(k + 0) * 64 + l];
            float w1 = sW2[(k + 1) * 64 + l];
            float w2 = sW2[(k + 2) * 64 + l];
            float w3 = sW2[(k + 3) * 64 + l];
#pragma unroll
            for (int r = 0; r < 8; r++) {
                float4 a = *(const float4*)&sr[r * 128 + k];
                acc[r] += a.x * w0 + a.y * w1 + a.z * w2 + a.w * w3;
            }
        }
        if (l < C_DIM) {
            int grow = rowbase + w * 8;
#pragma unroll
            for (int r = 0; r < 8; r++) xws[(grow + r) * C_DIM + l] = acc[r] * dinv[grow + r];
        }
    }
}

// ---------------- GCN conv + bias + log_softmax: wave/node, LDS ids, unroll 8 ----------------
// xws is dinv-prescaled: out_c = di*(sum_nbr xws[c] + xws[self]) + b2

__global__ __launch_bounds__(256) void k_gcn(const float* __restrict__ xws,
                                             const float* __restrict__ dinv,
                                             const int* __restrict__ scol,
                                             const int* __restrict__ off, const int* __restrict__ cnt,
                                             const float* __restrict__ b2,
                                             float* __restrict__ out) {
    __shared__ int sids[4][64];
    int wv = threadIdx.x >> 6;
    int wid = blockIdx.x * 4 + wv;
    int l = threadIdx.x & 63;
    if (wid >= N_NODES) return;
    int start = off[wid], len = cnt[wid];
    bool act = l < C_DIM;
    int lc = act ? l : 0;

    int n = len < 64 ? len : 64;
    sids[wv][l] = (l < n) ? scol[start + l] : 0;

    float s0 = 0.f, s1 = 0.f, s2 = 0.f, s3 = 0.f;
    int j = 0;
    for (; j + 8 <= n; j += 8) {
        int4 ca = *(const int4*)&sids[wv][j];
        int4 cb = *(const int4*)&sids[wv][j + 4];
        float t0 = xws[ca.x * C_DIM + lc];
        float t1 = xws[ca.y * C_DIM + lc];
        float t2 = xws[ca.z * C_DIM + lc];
        float t3 = xws[ca.w * C_DIM + lc];
        float t4 = xws[cb.x * C_DIM + lc];
        float t5 = xws[cb.y * C_DIM + lc];
        float t6 = xws[cb.z * C_DIM + lc];
        float t7 = xws[cb.w * C_DIM + lc];
        s0 += t0 + t4;
        s1 += t1 + t5;
        s2 += t2 + t6;
        s3 += t3 + t7;
    }
    for (; j + 4 <= n; j += 4) {
        int4 ca = *(const int4*)&sids[wv][j];
        s0 += xws[ca.x * C_DIM + lc];
        s1 += xws[ca.y * C_DIM + lc];
        s2 += xws[ca.z * C_DIM + lc];
        s3 += xws[ca.w * C_DIM + lc];
    }
    for (; j < n; j++) {
        s0 += xws[sids[wv][j] * C_DIM + lc];
    }
    for (int j2 = 64; j2 < len; j2++) {
        s0 += xws[scol[start + j2] * C_DIM + lc];
    }

    float di = dinv[wid];
    float s = (s0 + s1) + (s2 + s3) + xws[wid * C_DIM + lc];
    float val = act ? (di * s + b2[lc]) : -1e30f;

    float m = val;
#pragma unroll
    for (int o = 32; o > 0; o >>= 1) m = fmaxf(m, __shfl_xor(m, o, 64));
    float e = __expf(val - m);
#pragma unroll
    for (int o = 32; o > 0; o >>= 1) e += __shfl_xor(e, o, 64);
    if (act) {
        float lse = m + __logf(e);
        out[wid * C_DIM + l] = val - lse;
    }
}

// ---------------- launch ----------------

extern "C" void kernel_launch(void* const* d_in, const int* in_sizes, int n_in,
                              void* d_out, int out_size, void* d_ws, size_t ws_size,
                              hipStream_t stream) {
    const float* x = (const float*)d_in[0];
    const int* mask = (const int*)d_in[1];
    const int* eidx = (const int*)d_in[2];
    const float* W1 = (const float*)d_in[3];
    const float* b1 = (const float*)d_in[4];
    const float* W2 = (const float*)d_in[5];
    const float* b2 = (const float*)d_in[6];
    float* out = (float*)d_out;

    const int* row = eidx;
    const int* col = eidx + N_EDGES;

    char* base = (char*)d_ws;
    size_t o = 0;
    auto alloc = [&](size_t bytes) {
        void* p = base + o;
        o = (o + bytes + 255) & ~(size_t)255;
        return p;
    };
    int* cnt = (int*)alloc(N_NODES * 4);
    int* off = (int*)alloc(N_NODES * 4);
    int* fill = (int*)alloc(N_NODES * 4);
    float* dinv = (float*)alloc(N_NODES * 4);
    int* blksum = (int*)alloc(256 * 4);
    ull* mbits = (ull*)alloc(N_NODES * 16);
    int* scol = (int*)alloc(N_EDGES * 4);
    float* hbuf = (float*)alloc((size_t)N_NODES * F_DIM * 4);
    float* xws = (float*)alloc((size_t)N_NODES * C_DIM * 4);
    (void)ws_size;

    hipMemsetAsync(cnt, 0, N_NODES * 4, stream);

    int gE = (N_EDGES + 255) / 256;                 // 6250
    int gN = (N_NODES + 255) / 256;                 // 391
    int gWaveN = (N_NODES + 3) / 4;                 // 4 waves/block, wave per node

    k_hist<<<gE, 256, 0, stream>>>(row, cnt);
    k_scan1<<<NBLK_SCAN, 256, 0, stream>>>(cnt, off, blksum);
    k_scan2<<<1, 256, 0, stream>>>(blksum);
    k_scan3<<<gN, 256, 0, stream>>>(cnt, off, blksum, fill, dinv);
    k_scatter<<<gE, 256, 0, stream>>>(row, col, fill, scol);
    k_maskpack<<<(N_NODES * 64 + 255) / 256, 256, 0, stream>>>(mask, mbits);
    k_agg<<<gWaveN, 256, 0, stream>>>(x, mbits, scol, off, cnt, hbuf);
    k_gemm1<<<G1_GRID, 256, 0, stream>>>(hbuf, W1, b1);
    k_gemm2<<<G2_GRID, 256, 0, stream>>>(hbuf, W2, dinv, xws);
    k_gcn<<<gWaveN, 256, 0, stream>>>(xws, dinv, scol, off, cnt, b2, out);
}

// Round 4
// 583.772 us; speedup vs baseline: 1.4306x; 1.0595x over previous
//
#include <hip/hip_runtime.h>
#include <hip/hip_fp16.h>
#include <math.h>

#define N_NODES 100000
#define N_EDGES 1600000
#define F_DIM 128
#define C_DIM 40
#define SCAN_CHUNK 1024
#define NBLK_SCAN ((N_NODES + SCAN_CHUNK - 1) / SCAN_CHUNK)   // 98

typedef unsigned long long ull;

// ---------------- fused prep: edge histogram + mask pack + x -> premasked fp16 ----------------

#define G_HIST ((N_EDGES + 255) / 256)     // 6250
#define G_NODE ((N_NODES + 3) / 4)         // 25000 (wave per node)

__global__ __launch_bounds__(256) void k_prep(const int* __restrict__ row,
                                              const int* __restrict__ mask,
                                              const float* __restrict__ x,
                                              int* __restrict__ cnt,
                                              ull* __restrict__ mbits,
                                              __half* __restrict__ xh) {
    if (blockIdx.x < G_HIST) {
        int e = blockIdx.x * 256 + threadIdx.x;
        if (e < N_EDGES) atomicAdd(&cnt[row[e]], 1);
        return;
    }
    int nb = blockIdx.x - G_HIST;
    int wv = threadIdx.x >> 6;
    int l = threadIdx.x & 63;
    int wid = nb * 4 + wv;                 // < 100000 exactly
    int m0 = mask[wid * F_DIM + l];
    int m1 = mask[wid * F_DIM + 64 + l];
    float x0 = x[wid * F_DIM + l];
    float x1 = x[wid * F_DIM + 64 + l];
    ull b0 = __ballot(m0 != 0);
    ull b1 = __ballot(m1 != 0);
    if (l == 0) {
        mbits[wid * 2 + 0] = b0;
        mbits[wid * 2 + 1] = b1;
    }
    xh[wid * F_DIM + l]      = __float2half(m0 ? x0 : 0.0f);   // premasked
    xh[wid * F_DIM + 64 + l] = __float2half(m1 ? x1 : 0.0f);
}

// ---------------- scans ----------------

__global__ __launch_bounds__(256) void k_scan1(const int* __restrict__ cnt,
                                               int* __restrict__ off, int* __restrict__ blksum) {
    __shared__ int s[256];
    int t = threadIdx.x;
    int base = blockIdx.x * SCAN_CHUNK + t * 4;
    int v0 = (base + 0 < N_NODES) ? cnt[base + 0] : 0;
    int v1 = (base + 1 < N_NODES) ? cnt[base + 1] : 0;
    int v2 = (base + 2 < N_NODES) ? cnt[base + 2] : 0;
    int v3 = (base + 3 < N_NODES) ? cnt[base + 3] : 0;
    int s0 = v0, s1 = s0 + v1, s2 = s1 + v2, s3 = s2 + v3;
    s[t] = s3;
    __syncthreads();
    for (int d = 1; d < 256; d <<= 1) {
        int x = (t >= d) ? s[t - d] : 0;
        __syncthreads();
        s[t] += x;
        __syncthreads();
    }
    int excl = s[t] - s3;
    if (base + 0 < N_NODES) off[base + 0] = excl;
    if (base + 1 < N_NODES) off[base + 1] = excl + s0;
    if (base + 2 < N_NODES) off[base + 2] = excl + s1;
    if (base + 3 < N_NODES) off[base + 3] = excl + s2;
    if (t == 255) blksum[blockIdx.x] = s[255];
}

__global__ __launch_bounds__(256) void k_scan2(int* __restrict__ blksum) {
    __shared__ int s[256];
    int t = threadIdx.x;
    int v = (t < NBLK_SCAN) ? blksum[t] : 0;
    s[t] = v;
    __syncthreads();
    for (int d = 1; d < 256; d <<= 1) {
        int x = (t >= d) ? s[t - d] : 0;
        __syncthreads();
        s[t] += x;
        __syncthreads();
    }
    if (t < NBLK_SCAN) blksum[t] = s[t] - v;  // exclusive
}

__global__ __launch_bounds__(256) void k_scan3(const int* __restrict__ cnt, int* __restrict__ off,
                                               const int* __restrict__ blksum,
                                               int* __restrict__ fill, float* __restrict__ dinv) {
    int i = blockIdx.x * 256 + threadIdx.x;
    if (i < N_NODES) {
        int o = off[i] + blksum[i >> 10];
        off[i] = o;
        fill[i] = o;
        dinv[i] = rsqrtf((float)cnt[i] + 1.0f);   // GCN degree = in-row-count + self-loop
    }
}

__global__ __launch_bounds__(256) void k_scatter(const int* __restrict__ row, const int* __restrict__ col,
                                                 int* __restrict__ fill, int* __restrict__ scol) {
    int e = blockIdx.x * 256 + threadIdx.x;
    if (e < N_EDGES) {
        int r = row[e];
        int p = atomicAdd(&fill[r], 1);
        scol[p] = col[e];
    }
}

// ---------------- PaGNN masked-mean aggregation: wave/node, fp16 premasked gather ----------------
// xh is premasked: sum += xh directly; deg from mbits.

#define AGG_EDGE(W, H, AX, AY, IX, IY)                       \
    {                                                        \
        float2 v = __half22float2(H);                        \
        AX += v.x; AY += v.y;                                \
        IX += (int)((W) >> sh) & 1;                          \
        IY += (int)((W) >> (sh + 1)) & 1;                    \
    }

__global__ __launch_bounds__(256) void k_agg(const __half* __restrict__ xh,
                                             const ull* __restrict__ mbits,
                                             const int* __restrict__ scol,
                                             const int* __restrict__ off, const int* __restrict__ cnt,
                                             float* __restrict__ hbuf) {
    __shared__ int sids[4][64];
    int wv = threadIdx.x >> 6;
    int wid = blockIdx.x * 4 + wv;
    int l = threadIdx.x & 63;
    if (wid >= N_NODES) return;
    int start = off[wid], len = cnt[wid];
    int f = 2 * l;                // this lane owns features f, f+1
    int wsel = l >> 5;
    int sh = f & 63;
    const __half2* xp = (const __half2*)xh;   // index: node*64 + l

    int n = len < 64 ? len : 64;
    sids[wv][l] = (l < n) ? scol[start + l] : 0;

    float ax0 = 0.f, ay0 = 0.f, ax1 = 0.f, ay1 = 0.f;
    float ax2 = 0.f, ay2 = 0.f, ax3 = 0.f, ay3 = 0.f;
    int ix0 = 0, iy0 = 0, ix1 = 0, iy1 = 0;
    int ix2 = 0, iy2 = 0, ix3 = 0, iy3 = 0;

    int j = 0;
    for (; j + 8 <= n; j += 8) {
        int4 ca = *(const int4*)&sids[wv][j];
        int4 cb = *(const int4*)&sids[wv][j + 4];
        ull w0 = mbits[ca.x * 2 + wsel];
        ull w1 = mbits[ca.y * 2 + wsel];
        ull w2 = mbits[ca.z * 2 + wsel];
        ull w3 = mbits[ca.w * 2 + wsel];
        ull w4 = mbits[cb.x * 2 + wsel];
        ull w5 = mbits[cb.y * 2 + wsel];
        ull w6 = mbits[cb.z * 2 + wsel];
        ull w7 = mbits[cb.w * 2 + wsel];
        __half2 h0 = xp[ca.x * 64 + l];
        __half2 h1 = xp[ca.y * 64 + l];
        __half2 h2 = xp[ca.z * 64 + l];
        __half2 h3 = xp[ca.w * 64 + l];
        __half2 h4 = xp[cb.x * 64 + l];
        __half2 h5 = xp[cb.y * 64 + l];
        __half2 h6 = xp[cb.z * 64 + l];
        __half2 h7 = xp[cb.w * 64 + l];
        AGG_EDGE(w0, h0, ax0, ay0, ix0, iy0)
        AGG_EDGE(w1, h1, ax1, ay1, ix1, iy1)
        AGG_EDGE(w2, h2, ax2, ay2, ix2, iy2)
        AGG_EDGE(w3, h3, ax3, ay3, ix3, iy3)
        AGG_EDGE(w4, h4, ax0, ay0, ix0, iy0)
        AGG_EDGE(w5, h5, ax1, ay1, ix1, iy1)
        AGG_EDGE(w6, h6, ax2, ay2, ix2, iy2)
        AGG_EDGE(w7, h7, ax3, ay3, ix3, iy3)
    }
    for (; j + 4 <= n; j += 4) {
        int4 ca = *(const int4*)&sids[wv][j];
        ull w0 = mbits[ca.x * 2 + wsel];
        ull w1 = mbits[ca.y * 2 + wsel];
        ull w2 = mbits[ca.z * 2 + wsel];
        ull w3 = mbits[ca.w * 2 + wsel];
        __half2 h0 = xp[ca.x * 64 + l];
        __half2 h1 = xp[ca.y * 64 + l];
        __half2 h2 = xp[ca.z * 64 + l];
        __half2 h3 = xp[ca.w * 64 + l];
        AGG_EDGE(w0, h0, ax0, ay0, ix0, iy0)
        AGG_EDGE(w1, h1, ax1, ay1, ix1, iy1)
        AGG_EDGE(w2, h2, ax2, ay2, ix2, iy2)
        AGG_EDGE(w3, h3, ax3, ay3, ix3, iy3)
    }
    for (; j < n; j++) {
        int c = sids[wv][j];
        ull w = mbits[c * 2 + wsel];
        __half2 h = xp[c * 64 + l];
        AGG_EDGE(w, h, ax0, ay0, ix0, iy0)
    }
    for (int j2 = 64; j2 < len; j2++) {   // rare tail (degree > 64)
        int c = scol[start + j2];
        ull w = mbits[c * 2 + wsel];
        __half2 h = xp[c * 64 + l];
        AGG_EDGE(w, h, ax0, ay0, ix0, iy0)
    }

    float ax = (ax0 + ax1) + (ax2 + ax3);
    float ay = (ay0 + ay1) + (ay2 + ay3);
    float dx = (float)((ix0 + ix1) + (ix2 + ix3));
    float dy = (float)((iy0 + iy1) + (iy2 + iy3));
    float2 hn;
    hn.x = ax / fmaxf(dx, 1.0f);
    hn.y = ay / fmaxf(dy, 1.0f);
    *(float2*)(hbuf + wid * F_DIM + f) = hn;
}

// ---------------- GEMM1 (persistent): h = relu(hn @ W1 + b1), in-place ----------------

#define G1R 16
#define G1_TILES (N_NODES / G1R)   // 6250
#define G1_GRID 512

__global__ __launch_bounds__(256) void k_gemm1(float* __restrict__ hbuf,
                                               const float* __restrict__ W1,
                                               const float* __restrict__ b1) {
    __shared__ float sW[128 * 128];   // 64 KB, staged ONCE
    __shared__ float srow[G1R * 128]; // 8 KB
    __shared__ float sb[128];
    int t = threadIdx.x;
    for (int i = t; i < 4096; i += 256) ((float4*)sW)[i] = ((const float4*)W1)[i];
    if (t < 128) sb[t] = b1[t];

    int w = t >> 6, l = t & 63;
    int c4 = (l & 31) * 4;
    int rh = l >> 5;
    int r0 = w * 4 + rh * 2;
    const float* srA = &srow[r0 * 128];
    const float* srB = &srow[(r0 + 1) * 128];

    for (int tile = blockIdx.x; tile < G1_TILES; tile += G1_GRID) {
        int rowbase = tile * G1R;
        __syncthreads();   // protect srow from previous iter's readers
        for (int i = t; i < G1R * 128 / 4; i += 256)
            ((float4*)srow)[i] = ((const float4*)(hbuf + rowbase * F_DIM))[i];
        __syncthreads();

        float4 acc0 = {0.f, 0.f, 0.f, 0.f}, acc1 = {0.f, 0.f, 0.f, 0.f};
#pragma unroll 4
        for (int k = 0; k < 128; k++) {
            float4 wv2 = *(const float4*)&sW[k * 128 + c4];
            float a0 = srA[k];
            float a1 = srB[k];
            acc0.x += a0 * wv2.x; acc0.y += a0 * wv2.y; acc0.z += a0 * wv2.z; acc0.w += a0 * wv2.w;
            acc1.x += a1 * wv2.x; acc1.y += a1 * wv2.y; acc1.z += a1 * wv2.z; acc1.w += a1 * wv2.w;
        }
        float4 bb = *(const float4*)&sb[c4];
        float4 o0, o1;
        o0.x = fmaxf(acc0.x + bb.x, 0.f); o0.y = fmaxf(acc0.y + bb.y, 0.f);
        o0.z = fmaxf(acc0.z + bb.z, 0.f); o0.w = fmaxf(acc0.w + bb.w, 0.f);
        o1.x = fmaxf(acc1.x + bb.x, 0.f); o1.y = fmaxf(acc1.y + bb.y, 0.f);
        o1.z = fmaxf(acc1.z + bb.z, 0.f); o1.w = fmaxf(acc1.w + bb.w, 0.f);
        int gr = rowbase + r0;
        *(float4*)&hbuf[gr * F_DIM + c4] = o0;
        *(float4*)&hbuf[(gr + 1) * F_DIM + c4] = o1;
    }
}

// ---------------- GEMM2 (persistent): xws_h = fp16( dinv * (h @ W2) ) ----------------

#define G2R 32
#define G2_TILES (N_NODES / G2R)   // 3125
#define G2_GRID 512

__global__ __launch_bounds__(256) void k_gemm2(const float* __restrict__ hbuf,
                                               const float* __restrict__ W2,
                                               const float* __restrict__ dinv,
                                               __half* __restrict__ xws_h) {
    __shared__ float sW2[128 * 64];   // 32 KB, cols >=40 zero, staged ONCE
    __shared__ float srow[G2R * 128]; // 16 KB
    int t = threadIdx.x;
    for (int i = t; i < 8192; i += 256) {
        int k = i >> 6, c = i & 63;
        sW2[i] = (c < C_DIM) ? W2[k * C_DIM + c] : 0.0f;
    }
    int w = t >> 6, l = t & 63;
    const float* sr = &srow[w * 8 * 128];

    for (int tile = blockIdx.x; tile < G2_TILES; tile += G2_GRID) {
        int rowbase = tile * G2R;
        __syncthreads();
        for (int i = t; i < 1024; i += 256)
            ((float4*)srow)[i] = ((const float4*)(hbuf + rowbase * F_DIM))[i];
        __syncthreads();

        float acc[8] = {0.f, 0.f, 0.f, 0.f, 0.f, 0.f, 0.f, 0.f};
        for (int k = 0; k < 128; k += 4) {
            float w0 = sW2[(k + 0) * 64 + l];
            float w1 = sW2[(k + 1) * 64 + l];
            float w2 = sW2[(k + 2) * 64 + l];
            float w3 = sW2[(k + 3) * 64 + l];
#pragma unroll
            for (int r = 0; r < 8; r++) {
                float4 a = *(const float4*)&sr[r * 128 + k];
                acc[r] += a.x * w0 + a.y * w1 + a.z * w2 + a.w * w3;
            }
        }
        if (l < C_DIM) {
            int grow = rowbase + w * 8;
#pragma unroll
            for (int r = 0; r < 8; r++)
                xws_h[(grow + r) * C_DIM + l] = __float2half(acc[r] * dinv[grow + r]);
        }
    }
}

// ---------------- GCN conv + bias + log_softmax: wave/node, 2 classes/lane fp16 ----------------
// xws_h is dinv-prescaled: out_c = di*(sum_nbr xws[c] + xws[self]) + b2

__global__ __launch_bounds__(256) void k_gcn(const __half* __restrict__ xws_h,
                                             const float* __restrict__ dinv,
                                             const int* __restrict__ scol,
                                             const int* __restrict__ off, const int* __restrict__ cnt,
                                             const float* __restrict__ b2,
                                             float* __restrict__ out) {
    __shared__ int sids[4][64];
    int wv = threadIdx.x >> 6;
    int wid = blockIdx.x * 4 + wv;
    int l = threadIdx.x & 63;
    if (wid >= N_NODES) return;
    int start = off[wid], len = cnt[wid];
    bool act = l < (C_DIM / 2);           // lanes 0..19 own classes 2l, 2l+1
    int ll = act ? l : 0;
    const __half2* xp = (const __half2*)xws_h;   // index: node*20 + ll

    int n = len < 64 ? len : 64;
    sids[wv][l] = (l < n) ? scol[start + l] : 0;

    float sx0 = 0.f, sy0 = 0.f, sx1 = 0.f, sy1 = 0.f;
    float sx2 = 0.f, sy2 = 0.f, sx3 = 0.f, sy3 = 0.f;
    int j = 0;
    for (; j + 8 <= n; j += 8) {
        int4 ca = *(const int4*)&sids[wv][j];
        int4 cb = *(const int4*)&sids[wv][j + 4];
        float2 t0 = __half22float2(xp[ca.x * 20 + ll]);
        float2 t1 = __half22float2(xp[ca.y * 20 + ll]);
        float2 t2 = __half22float2(xp[ca.z * 20 + ll]);
        float2 t3 = __half22float2(xp[ca.w * 20 + ll]);
        float2 t4 = __half22float2(xp[cb.x * 20 + ll]);
        float2 t5 = __half22float2(xp[cb.y * 20 + ll]);
        float2 t6 = __half22float2(xp[cb.z * 20 + ll]);
        float2 t7 = __half22float2(xp[cb.w * 20 + ll]);
        sx0 += t0.x + t4.x; sy0 += t0.y + t4.y;
        sx1 += t1.x + t5.x; sy1 += t1.y + t5.y;
        sx2 += t2.x + t6.x; sy2 += t2.y + t6.y;
        sx3 += t3.x + t7.x; sy3 += t3.y + t7.y;
    }
    for (; j + 4 <= n; j += 4) {
        int4 ca = *(const int4*)&sids[wv][j];
        float2 t0 = __half22float2(xp[ca.x * 20 + ll]);
        float2 t1 = __half22float2(xp[ca.y * 20 + ll]);
        float2 t2 = __half22float2(xp[ca.z * 20 + ll]);
        float2 t3 = __half22float2(xp[ca.w * 20 + ll]);
        sx0 += t0.x; sy0 += t0.y;
        sx1 += t1.x; sy1 += t1.y;
        sx2 += t2.x; sy2 += t2.y;
        sx3 += t3.x; sy3 += t3.y;
    }
    for (; j < n; j++) {
        float2 t0 = __half22float2(xp[sids[wv][j] * 20 + ll]);
        sx0 += t0.x; sy0 += t0.y;
    }
    for (int j2 = 64; j2 < len; j2++) {
        float2 t0 = __half22float2(xp[scol[start + j2] * 20 + ll]);
        sx0 += t0.x; sy0 += t0.y;
    }

    float di = dinv[wid];
    float2 self = __half22float2(xp[wid * 20 + ll]);
    float sx = (sx0 + sx1) + (sx2 + sx3) + self.x;
    float sy = (sy0 + sy1) + (sy2 + sy3) + self.y;
    float2 bb = act ? ((const float2*)b2)[ll] : make_float2(0.f, 0.f);
    float val0 = di * sx + bb.x;
    float val1 = di * sy + bb.y;

    float m = act ? fmaxf(val0, val1) : -1e30f;
#pragma unroll
    for (int o = 32; o > 0; o >>= 1) m = fmaxf(m, __shfl_xor(m, o, 64));
    float e = act ? (__expf(val0 - m) + __expf(val1 - m)) : 0.0f;
#pragma unroll
    for (int o = 32; o > 0; o >>= 1) e += __shfl_xor(e, o, 64);
    if (act) {
        float lse = m + __logf(e);
        float2 o2 = make_float2(val0 - lse, val1 - lse);
        ((float2*)out)[wid * 20 + l] = o2;
    }
}

// ---------------- launch ----------------

extern "C" void kernel_launch(void* const* d_in, const int* in_sizes, int n_in,
                              void* d_out, int out_size, void* d_ws, size_t ws_size,
                              hipStream_t stream) {
    const float* x = (const float*)d_in[0];
    const int* mask = (const int*)d_in[1];
    const int* eidx = (const int*)d_in[2];
    const float* W1 = (const float*)d_in[3];
    const float* b1 = (const float*)d_in[4];
    const float* W2 = (const float*)d_in[5];
    const float* b2 = (const float*)d_in[6];
    float* out = (float*)d_out;

    const int* row = eidx;
    const int* col = eidx + N_EDGES;

    char* base = (char*)d_ws;
    size_t o = 0;
    auto alloc = [&](size_t bytes) {
        void* p = base + o;
        o = (o + bytes + 255) & ~(size_t)255;
        return p;
    };
    int* cnt = (int*)alloc(N_NODES * 4);
    int* off = (int*)alloc(N_NODES * 4);
    int* fill = (int*)alloc(N_NODES * 4);
    float* dinv = (float*)alloc(N_NODES * 4);
    int* blksum = (int*)alloc(256 * 4);
    ull* mbits = (ull*)alloc(N_NODES * 16);
    int* scol = (int*)alloc(N_EDGES * 4);
    __half* xh = (__half*)alloc((size_t)N_NODES * F_DIM * 2);
    float* hbuf = (float*)alloc((size_t)N_NODES * F_DIM * 4);
    __half* xws_h = (__half*)alloc((size_t)N_NODES * C_DIM * 2);
    (void)ws_size;

    hipMemsetAsync(cnt, 0, N_NODES * 4, stream);

    int gE = (N_EDGES + 255) / 256;                 // 6250
    int gN = (N_NODES + 255) / 256;                 // 391

    k_prep<<<G_HIST + G_NODE, 256, 0, stream>>>(row, mask, x, cnt, mbits, xh);
    k_scan1<<<NBLK_SCAN, 256, 0, stream>>>(cnt, off, blksum);
    k_scan2<<<1, 256, 0, stream>>>(blksum);
    k_scan3<<<gN, 256, 0, stream>>>(cnt, off, blksum, fill, dinv);
    k_scatter<<<gE, 256, 0, stream>>>(row, col, fill, scol);
    k_agg<<<G_NODE, 256, 0, stream>>>(xh, mbits, scol, off, cnt, hbuf);
    k_gemm1<<<G1_GRID, 256, 0, stream>>>(hbuf, W1, b1);
    k_gemm2<<<G2_GRID, 256, 0, stream>>>(hbuf, W2, dinv, xws_h);
    k_gcn<<<G_NODE, 256, 0, stream>>>(xws_h, dinv, scol, off, cnt, b2, out);
}

// Round 5
// 506.002 us; speedup vs baseline: 1.6505x; 1.1537x over previous
//
#include <hip/hip_runtime.h>
#include <hip/hip_fp16.h>
#include <math.h>

#define N_NODES 100000
#define N_EDGES 1600000
#define F_DIM 128
#define C_DIM 40
#define SCAN_CHUNK 1024
#define NBLK_SCAN ((N_NODES + SCAN_CHUNK - 1) / SCAN_CHUNK)   // 98

#define NBUCK 782            // ceil(100000 / 128) row-buckets of 128 rows
#define EB 4096              // edges per k_bucket block
#define NBLK_BUCKET ((N_EDGES + EB - 1) / EB)   // 391
#define BCAP 4096            // k_bsort LDS staging capacity (max bucket ~2.3k)

typedef unsigned long long ull;

// ---------------- fused prep: edge histogram + mask pack + x -> premasked fp16 ----------------

#define G_HIST ((N_EDGES + 255) / 256)     // 6250
#define G_NODE ((N_NODES + 3) / 4)         // 25000 (wave per node)

__global__ __launch_bounds__(256) void k_prep(const int* __restrict__ row,
                                              const int* __restrict__ mask,
                                              const float* __restrict__ x,
                                              int* __restrict__ cnt,
                                              ull* __restrict__ mbits,
                                              __half* __restrict__ xh) {
    if (blockIdx.x < G_HIST) {
        int e = blockIdx.x * 256 + threadIdx.x;
        if (e < N_EDGES) atomicAdd(&cnt[row[e]], 1);
        return;
    }
    int nb = blockIdx.x - G_HIST;
    int wv = threadIdx.x >> 6;
    int l = threadIdx.x & 63;
    int wid = nb * 4 + wv;                 // < 100000 exactly
    int m0 = mask[wid * F_DIM + l];
    int m1 = mask[wid * F_DIM + 64 + l];
    float x0 = x[wid * F_DIM + l];
    float x1 = x[wid * F_DIM + 64 + l];
    ull b0 = __ballot(m0 != 0);
    ull b1 = __ballot(m1 != 0);
    if (l == 0) {
        mbits[wid * 2 + 0] = b0;
        mbits[wid * 2 + 1] = b1;
    }
    xh[wid * F_DIM + l]      = __float2half(m0 ? x0 : 0.0f);   // premasked
    xh[wid * F_DIM + 64 + l] = __float2half(m1 ? x1 : 0.0f);
}

// ---------------- scans ----------------

__global__ __launch_bounds__(256) void k_scan1(const int* __restrict__ cnt,
                                               int* __restrict__ off, int* __restrict__ blksum) {
    __shared__ int s[256];
    int t = threadIdx.x;
    int base = blockIdx.x * SCAN_CHUNK + t * 4;
    int v0 = (base + 0 < N_NODES) ? cnt[base + 0] : 0;
    int v1 = (base + 1 < N_NODES) ? cnt[base + 1] : 0;
    int v2 = (base + 2 < N_NODES) ? cnt[base + 2] : 0;
    int v3 = (base + 3 < N_NODES) ? cnt[base + 3] : 0;
    int s0 = v0, s1 = s0 + v1, s2 = s1 + v2, s3 = s2 + v3;
    s[t] = s3;
    __syncthreads();
    for (int d = 1; d < 256; d <<= 1) {
        int x = (t >= d) ? s[t - d] : 0;
        __syncthreads();
        s[t] += x;
        __syncthreads();
    }
    int excl = s[t] - s3;
    if (base + 0 < N_NODES) off[base + 0] = excl;
    if (base + 1 < N_NODES) off[base + 1] = excl + s0;
    if (base + 2 < N_NODES) off[base + 2] = excl + s1;
    if (base + 3 < N_NODES) off[base + 3] = excl + s2;
    if (t == 255) blksum[blockIdx.x] = s[255];
}

__global__ __launch_bounds__(256) void k_scan2(int* __restrict__ blksum) {
    __shared__ int s[256];
    int t = threadIdx.x;
    int v = (t < NBLK_SCAN) ? blksum[t] : 0;
    s[t] = v;
    __syncthreads();
    for (int d = 1; d < 256; d <<= 1) {
        int x = (t >= d) ? s[t - d] : 0;
        __syncthreads();
        s[t] += x;
        __syncthreads();
    }
    if (t < NBLK_SCAN) blksum[t] = s[t] - v;  // exclusive
}

__global__ __launch_bounds__(256) void k_scan3(const int* __restrict__ cnt, int* __restrict__ off,
                                               const int* __restrict__ blksum,
                                               float* __restrict__ dinv, int* __restrict__ bfill) {
    int i = blockIdx.x * 256 + threadIdx.x;
    if (i < N_NODES) {
        int o = off[i] + blksum[i >> 10];
        off[i] = o;
        if ((i & 127) == 0) bfill[i >> 7] = o;   // bucket write cursor = bucket CSR base
        dinv[i] = rsqrtf((float)cnt[i] + 1.0f);  // GCN degree = in-row-count + self-loop
    }
}

// ---------------- CSR build phase A: per-block counting sort into coarse buckets ----------------
// Writes packed (col<<32 | row) pairs as contiguous runs into each bucket's CSR region.
// Order within a bucket (and within a row) is arbitrary — aggregation sums commute.

__global__ __launch_bounds__(256) void k_bucket(const int* __restrict__ row,
                                                const int* __restrict__ col,
                                                int* __restrict__ bfill,
                                                ull* __restrict__ ebuf) {
    __shared__ int lhist[1024];     // bucket hist, then reused as per-bucket fill
    __shared__ int lscan[1024];
    __shared__ int gbase[NBUCK];
    __shared__ ull stage[EB];       // 32 KB
    __shared__ int partial[256];
    int t = threadIdx.x;
    int base = blockIdx.x * EB;
    int cnt = min(EB, N_EDGES - base);

    for (int i = t; i < 1024; i += 256) lhist[i] = 0;
    __syncthreads();
    for (int i = t; i < cnt; i += 256)
        atomicAdd(&lhist[row[base + i] >> 7], 1);
    __syncthreads();

    // exclusive scan over 1024 bins (4 bins/thread + block Hillis-Steele)
    int b4 = t * 4;
    int h0 = lhist[b4], h1 = lhist[b4 + 1], h2 = lhist[b4 + 2], h3 = lhist[b4 + 3];
    int s3 = h0 + h1 + h2 + h3;
    partial[t] = s3;
    __syncthreads();
    for (int d = 1; d < 256; d <<= 1) {
        int xv = (t >= d) ? partial[t - d] : 0;
        __syncthreads();
        partial[t] += xv;
        __syncthreads();
    }
    int excl = partial[t] - s3;
    lscan[b4] = excl;
    lscan[b4 + 1] = excl + h0;
    lscan[b4 + 2] = excl + h0 + h1;
    lscan[b4 + 3] = excl + h0 + h1 + h2;
    __syncthreads();

    for (int i = t; i < 1024; i += 256) lhist[i] = 0;   // now per-bucket fill
    __syncthreads();

    // scatter chunk into bucket-major LDS staging
    for (int i = t; i < cnt; i += 256) {
        int r = row[base + i];
        int c = col[base + i];
        int b = r >> 7;
        int p = lscan[b] + atomicAdd(&lhist[b], 1);
        stage[p] = ((ull)(unsigned)c << 32) | (unsigned)r;
    }
    __syncthreads();

    // one global atomic per non-empty (block,bucket) run
    for (int b = t; b < NBUCK; b += 256) {
        int c = lhist[b];
        gbase[b] = c ? atomicAdd(&bfill[b], c) : 0;
    }
    __syncthreads();

    // stream runs out (consecutive i -> mostly consecutive dst)
    for (int i = t; i < cnt; i += 256) {
        ull pk = stage[i];
        int b = ((int)(unsigned)(pk & 0xffffffffull)) >> 7;
        int dst = gbase[b] + (i - lscan[b]);
        ebuf[dst] = pk;
    }
}

// ---------------- CSR build phase B: in-bucket scatter to exact row segments ----------------

__global__ __launch_bounds__(256) void k_bsort(const ull* __restrict__ ebuf,
                                               const int* __restrict__ off,
                                               int* __restrict__ scol) {
    __shared__ int lfill[128];
    __shared__ int lcol[BCAP];
    int b = blockIdx.x;
    int rowbase = b << 7;
    int rowend = min(rowbase + 128, N_NODES);
    int segstart = off[rowbase];
    int segend = (rowend < N_NODES) ? off[rowend] : N_EDGES;
    int m = segend - segstart;
    int t = threadIdx.x;
    if (t < 128) {
        int r = rowbase + t;
        lfill[t] = (r < N_NODES) ? (off[r] - segstart) : 0;
    }
    __syncthreads();
    for (int i = t; i < m; i += 256) {
        ull pk = ebuf[segstart + i];
        int r = (int)(unsigned)(pk & 0xffffffffull);
        int c = (int)(unsigned)(pk >> 32);
        int p = atomicAdd(&lfill[r & 127], 1);
        if (p < BCAP) lcol[p] = c;
        else scol[segstart + p] = c;    // never for uniform-random graphs
    }
    __syncthreads();
    int mm = m < BCAP ? m : BCAP;
    for (int i = t; i < mm; i += 256) scol[segstart + i] = lcol[i];
}

// ---------------- PaGNN masked-mean aggregation: wave/node, fp16 premasked gather ----------------

#define AGG_EDGE(W, H, AX, AY, IX, IY)                       \
    {                                                        \
        float2 v = __half22float2(H);                        \
        AX += v.x; AY += v.y;                                \
        IX += (int)((W) >> sh) & 1;                          \
        IY += (int)((W) >> (sh + 1)) & 1;                    \
    }

__global__ __launch_bounds__(256) void k_agg(const __half* __restrict__ xh,
                                             const ull* __restrict__ mbits,
                                             const int* __restrict__ scol,
                                             const int* __restrict__ off, const int* __restrict__ cnt,
                                             float* __restrict__ hbuf) {
    __shared__ int sids[4][64];
    int wv = threadIdx.x >> 6;
    int wid = blockIdx.x * 4 + wv;
    int l = threadIdx.x & 63;
    if (wid >= N_NODES) return;
    int start = off[wid], len = cnt[wid];
    int f = 2 * l;                // this lane owns features f, f+1
    int wsel = l >> 5;
    int sh = f & 63;
    const __half2* xp = (const __half2*)xh;   // index: node*64 + l

    int n = len < 64 ? len : 64;
    sids[wv][l] = (l < n) ? scol[start + l] : 0;

    float ax0 = 0.f, ay0 = 0.f, ax1 = 0.f, ay1 = 0.f;
    float ax2 = 0.f, ay2 = 0.f, ax3 = 0.f, ay3 = 0.f;
    int ix0 = 0, iy0 = 0, ix1 = 0, iy1 = 0;
    int ix2 = 0, iy2 = 0, ix3 = 0, iy3 = 0;

    int j = 0;
    for (; j + 8 <= n; j += 8) {
        int4 ca = *(const int4*)&sids[wv][j];
        int4 cb = *(const int4*)&sids[wv][j + 4];
        ull w0 = mbits[ca.x * 2 + wsel];
        ull w1 = mbits[ca.y * 2 + wsel];
        ull w2 = mbits[ca.z * 2 + wsel];
        ull w3 = mbits[ca.w * 2 + wsel];
        ull w4 = mbits[cb.x * 2 + wsel];
        ull w5 = mbits[cb.y * 2 + wsel];
        ull w6 = mbits[cb.z * 2 + wsel];
        ull w7 = mbits[cb.w * 2 + wsel];
        __half2 h0 = xp[ca.x * 64 + l];
        __half2 h1 = xp[ca.y * 64 + l];
        __half2 h2 = xp[ca.z * 64 + l];
        __half2 h3 = xp[ca.w * 64 + l];
        __half2 h4 = xp[cb.x * 64 + l];
        __half2 h5 = xp[cb.y * 64 + l];
        __half2 h6 = xp[cb.z * 64 + l];
        __half2 h7 = xp[cb.w * 64 + l];
        AGG_EDGE(w0, h0, ax0, ay0, ix0, iy0)
        AGG_EDGE(w1, h1, ax1, ay1, ix1, iy1)
        AGG_EDGE(w2, h2, ax2, ay2, ix2, iy2)
        AGG_EDGE(w3, h3, ax3, ay3, ix3, iy3)
        AGG_EDGE(w4, h4, ax0, ay0, ix0, iy0)
        AGG_EDGE(w5, h5, ax1, ay1, ix1, iy1)
        AGG_EDGE(w6, h6, ax2, ay2, ix2, iy2)
        AGG_EDGE(w7, h7, ax3, ay3, ix3, iy3)
    }
    for (; j + 4 <= n; j += 4) {
        int4 ca = *(const int4*)&sids[wv][j];
        ull w0 = mbits[ca.x * 2 + wsel];
        ull w1 = mbits[ca.y * 2 + wsel];
        ull w2 = mbits[ca.z * 2 + wsel];
        ull w3 = mbits[ca.w * 2 + wsel];
        __half2 h0 = xp[ca.x * 64 + l];
        __half2 h1 = xp[ca.y * 64 + l];
        __half2 h2 = xp[ca.z * 64 + l];
        __half2 h3 = xp[ca.w * 64 + l];
        AGG_EDGE(w0, h0, ax0, ay0, ix0, iy0)
        AGG_EDGE(w1, h1, ax1, ay1, ix1, iy1)
        AGG_EDGE(w2, h2, ax2, ay2, ix2, iy2)
        AGG_EDGE(w3, h3, ax3, ay3, ix3, iy3)
    }
    for (; j < n; j++) {
        int c = sids[wv][j];
        ull w = mbits[c * 2 + wsel];
        __half2 h = xp[c * 64 + l];
        AGG_EDGE(w, h, ax0, ay0, ix0, iy0)
    }
    for (int j2 = 64; j2 < len; j2++) {   // rare tail (degree > 64)
        int c = scol[start + j2];
        ull w = mbits[c * 2 + wsel];
        __half2 h = xp[c * 64 + l];
        AGG_EDGE(w, h, ax0, ay0, ix0, iy0)
    }

    float ax = (ax0 + ax1) + (ax2 + ax3);
    float ay = (ay0 + ay1) + (ay2 + ay3);
    float dx = (float)((ix0 + ix1) + (ix2 + ix3));
    float dy = (float)((iy0 + iy1) + (iy2 + iy3));
    float2 hn;
    hn.x = ax / fmaxf(dx, 1.0f);
    hn.y = ay / fmaxf(dy, 1.0f);
    *(float2*)(hbuf + wid * F_DIM + f) = hn;
}

// ---------------- GEMM1 (persistent): h = relu(hn @ W1 + b1), in-place ----------------

#define G1R 16
#define G1_TILES (N_NODES / G1R)   // 6250
#define G1_GRID 512

__global__ __launch_bounds__(256) void k_gemm1(float* __restrict__ hbuf,
                                               const float* __restrict__ W1,
                                               const float* __restrict__ b1) {
    __shared__ float sW[128 * 128];   // 64 KB, staged ONCE
    __shared__ float srow[G1R * 128]; // 8 KB
    __shared__ float sb[128];
    int t = threadIdx.x;
    for (int i = t; i < 4096; i += 256) ((float4*)sW)[i] = ((const float4*)W1)[i];
    if (t < 128) sb[t] = b1[t];

    int w = t >> 6, l = t & 63;
    int c4 = (l & 31) * 4;
    int rh = l >> 5;
    int r0 = w * 4 + rh * 2;
    const float* srA = &srow[r0 * 128];
    const float* srB = &srow[(r0 + 1) * 128];

    for (int tile = blockIdx.x; tile < G1_TILES; tile += G1_GRID) {
        int rowbase = tile * G1R;
        __syncthreads();   // protect srow from previous iter's readers
        for (int i = t; i < G1R * 128 / 4; i += 256)
            ((float4*)srow)[i] = ((const float4*)(hbuf + rowbase * F_DIM))[i];
        __syncthreads();

        float4 acc0 = {0.f, 0.f, 0.f, 0.f}, acc1 = {0.f, 0.f, 0.f, 0.f};
#pragma unroll 4
        for (int k = 0; k < 128; k++) {
            float4 wv2 = *(const float4*)&sW[k * 128 + c4];
            float a0 = srA[k];
            float a1 = srB[k];
            acc0.x += a0 * wv2.x; acc0.y += a0 * wv2.y; acc0.z += a0 * wv2.z; acc0.w += a0 * wv2.w;
            acc1.x += a1 * wv2.x; acc1.y += a1 * wv2.y; acc1.z += a1 * wv2.z; acc1.w += a1 * wv2.w;
        }
        float4 bb = *(const float4*)&sb[c4];
        float4 o0, o1;
        o0.x = fmaxf(acc0.x + bb.x, 0.f); o0.y = fmaxf(acc0.y + bb.y, 0.f);
        o0.z = fmaxf(acc0.z + bb.z, 0.f); o0.w = fmaxf(acc0.w + bb.w, 0.f);
        o1.x = fmaxf(acc1.x + bb.x, 0.f); o1.y = fmaxf(acc1.y + bb.y, 0.f);
        o1.z = fmaxf(acc1.z + bb.z, 0.f); o1.w = fmaxf(acc1.w + bb.w, 0.f);
        int gr = rowbase + r0;
        *(float4*)&hbuf[gr * F_DIM + c4] = o0;
        *(float4*)&hbuf[(gr + 1) * F_DIM + c4] = o1;
    }
}

// ---------------- GEMM2 (persistent): xws_h = fp16( dinv * (h @ W2) ) ----------------

#define G2R 32
#define G2_TILES (N_NODES / G2R)   // 3125
#define G2_GRID 512

__global__ __launch_bounds__(256) void k_gemm2(const float* __restrict__ hbuf,
                                               const float* __restrict__ W2,
                                               const float* __restrict__ dinv,
                                               __half* __restrict__ xws_h) {
    __shared__ float sW2[128 * 64];   // 32 KB, cols >=40 zero, staged ONCE
    __shared__ float srow[G2R * 128]; // 16 KB
    int t = threadIdx.x;
    for (int i = t; i < 8192; i += 256) {
        int k = i >> 6, c = i & 63;
        sW2[i] = (c < C_DIM) ? W2[k * C_DIM + c] : 0.0f;
    }
    int w = t >> 6, l = t & 63;
    const float* sr = &srow[w * 8 * 128];

    for (int tile = blockIdx.x; tile < G2_TILES; tile += G2_GRID) {
        int rowbase = tile * G2R;
        __syncthreads();
        for (int i = t; i < 1024; i += 256)
            ((float4*)srow)[i] = ((const float4*)(hbuf + rowbase * F_DIM))[i];
        __syncthreads();

        float acc[8] = {0.f, 0.f, 0.f, 0.f, 0.f, 0.f, 0.f, 0.f};
        for (int k = 0; k < 128; k += 4) {
            float w0 = sW2[(k + 0) * 64 + l];
            float w1 = sW2[(k + 1) * 64 + l];
            float w2 = sW2[(k + 2) * 64 + l];
            float w3 = sW2[(k + 3) * 64 + l];
#pragma unroll
            for (int r = 0; r < 8; r++) {
                float4 a = *(const float4*)&sr[r * 128 + k];
                acc[r] += a.x * w0 + a.y * w1 + a.z * w2 + a.w * w3;
            }
        }
        if (l < C_DIM) {
            int grow = rowbase + w * 8;
#pragma unroll
            for (int r = 0; r < 8; r++)
                xws_h[(grow + r) * C_DIM + l] = __float2half(acc[r] * dinv[grow + r]);
        }
    }
}

// ---------------- GCN conv + bias + log_softmax: wave/node, 2 classes/lane fp16 ----------------

__global__ __launch_bounds__(256) void k_gcn(const __half* __restrict__ xws_h,
                                             const float* __restrict__ dinv,
                                             const int* __restrict__ scol,
                                             const int* __restrict__ off, const int* __restrict__ cnt,
                                             const float* __restrict__ b2,
                                             float* __restrict__ out) {
    __shared__ int sids[4][64];
    int wv = threadIdx.x >> 6;
    int wid = blockIdx.x * 4 + wv;
    int l = threadIdx.x & 63;
    if (wid >= N_NODES) return;
    int start = off[wid], len = cnt[wid];
    bool act = l < (C_DIM / 2);           // lanes 0..19 own classes 2l, 2l+1
    int ll = act ? l : 0;
    const __half2* xp = (const __half2*)xws_h;   // index: node*20 + ll

    int n = len < 64 ? len : 64;
    sids[wv][l] = (l < n) ? scol[start + l] : 0;

    float sx0 = 0.f, sy0 = 0.f, sx1 = 0.f, sy1 = 0.f;
    float sx2 = 0.f, sy2 = 0.f, sx3 = 0.f, sy3 = 0.f;
    int j = 0;
    for (; j + 8 <= n; j += 8) {
        int4 ca = *(const int4*)&sids[wv][j];
        int4 cb = *(const int4*)&sids[wv][j + 4];
        float2 t0 = __half22float2(xp[ca.x * 20 + ll]);
        float2 t1 = __half22float2(xp[ca.y * 20 + ll]);
        float2 t2 = __half22float2(xp[ca.z * 20 + ll]);
        float2 t3 = __half22float2(xp[ca.w * 20 + ll]);
        float2 t4 = __half22float2(xp[cb.x * 20 + ll]);
        float2 t5 = __half22float2(xp[cb.y * 20 + ll]);
        float2 t6 = __half22float2(xp[cb.z * 20 + ll]);
        float2 t7 = __half22float2(xp[cb.w * 20 + ll]);
        sx0 += t0.x + t4.x; sy0 += t0.y + t4.y;
        sx1 += t1.x + t5.x; sy1 += t1.y + t5.y;
        sx2 += t2.x + t6.x; sy2 += t2.y + t6.y;
        sx3 += t3.x + t7.x; sy3 += t3.y + t7.y;
    }
    for (; j + 4 <= n; j += 4) {
        int4 ca = *(const int4*)&sids[wv][j];
        float2 t0 = __half22float2(xp[ca.x * 20 + ll]);
        float2 t1 = __half22float2(xp[ca.y * 20 + ll]);
        float2 t2 = __half22float2(xp[ca.z * 20 + ll]);
        float2 t3 = __half22float2(xp[ca.w * 20 + ll]);
        sx0 += t0.x; sy0 += t0.y;
        sx1 += t1.x; sy1 += t1.y;
        sx2 += t2.x; sy2 += t2.y;
        sx3 += t3.x; sy3 += t3.y;
    }
    for (; j < n; j++) {
        float2 t0 = __half22float2(xp[sids[wv][j] * 20 + ll]);
        sx0 += t0.x; sy0 += t0.y;
    }
    for (int j2 = 64; j2 < len; j2++) {
        float2 t0 = __half22float2(xp[scol[start + j2] * 20 + ll]);
        sx0 += t0.x; sy0 += t0.y;
    }

    float di = dinv[wid];
    float2 self = __half22float2(xp[wid * 20 + ll]);
    float sx = (sx0 + sx1) + (sx2 + sx3) + self.x;
    float sy = (sy0 + sy1) + (sy2 + sy3) + self.y;
    float2 bb = act ? ((const float2*)b2)[ll] : make_float2(0.f, 0.f);
    float val0 = di * sx + bb.x;
    float val1 = di * sy + bb.y;

    float m = act ? fmaxf(val0, val1) : -1e30f;
#pragma unroll
    for (int o = 32; o > 0; o >>= 1) m = fmaxf(m, __shfl_xor(m, o, 64));
    float e = act ? (__expf(val0 - m) + __expf(val1 - m)) : 0.0f;
#pragma unroll
    for (int o = 32; o > 0; o >>= 1) e += __shfl_xor(e, o, 64);
    if (act) {
        float lse = m + __logf(e);
        float2 o2 = make_float2(val0 - lse, val1 - lse);
        ((float2*)out)[wid * 20 + l] = o2;
    }
}

// ---------------- launch ----------------

extern "C" void kernel_launch(void* const* d_in, const int* in_sizes, int n_in,
                              void* d_out, int out_size, void* d_ws, size_t ws_size,
                              hipStream_t stream) {
    const float* x = (const float*)d_in[0];
    const int* mask = (const int*)d_in[1];
    const int* eidx = (const int*)d_in[2];
    const float* W1 = (const float*)d_in[3];
    const float* b1 = (const float*)d_in[4];
    const float* W2 = (const float*)d_in[5];
    const float* b2 = (const float*)d_in[6];
    float* out = (float*)d_out;

    const int* row = eidx;
    const int* col = eidx + N_EDGES;

    char* base = (char*)d_ws;
    size_t o = 0;
    auto alloc = [&](size_t bytes) {
        void* p = base + o;
        o = (o + bytes + 255) & ~(size_t)255;
        return p;
    };
    int* cnt = (int*)alloc(N_NODES * 4);
    int* off = (int*)alloc(N_NODES * 4);
    float* dinv = (float*)alloc(N_NODES * 4);
    int* blksum = (int*)alloc(256 * 4);
    int* bfill = (int*)alloc(NBUCK * 4);
    ull* mbits = (ull*)alloc(N_NODES * 16);
    int* scol = (int*)alloc(N_EDGES * 4);
    __half* xh = (__half*)alloc((size_t)N_NODES * F_DIM * 2);
    float* hbuf = (float*)alloc((size_t)N_NODES * F_DIM * 4);
    __half* xws_h = (__half*)alloc((size_t)N_NODES * C_DIM * 2);
    (void)ws_size;

    ull* ebuf = (ull*)hbuf;   // alias: ebuf dead before k_agg writes hbuf (12.8 MB <= 51.2 MB)

    hipMemsetAsync(cnt, 0, N_NODES * 4, stream);

    int gN = (N_NODES + 255) / 256;                 // 391

    k_prep<<<G_HIST + G_NODE, 256, 0, stream>>>(row, mask, x, cnt, mbits, xh);
    k_scan1<<<NBLK_SCAN, 256, 0, stream>>>(cnt, off, blksum);
    k_scan2<<<1, 256, 0, stream>>>(blksum);
    k_scan3<<<gN, 256, 0, stream>>>(cnt, off, blksum, dinv, bfill);
    k_bucket<<<NBLK_BUCKET, 256, 0, stream>>>(row, col, bfill, ebuf);
    k_bsort<<<NBUCK, 256, 0, stream>>>(ebuf, off, scol);
    k_agg<<<G_NODE, 256, 0, stream>>>(xh, mbits, scol, off, cnt, hbuf);
    k_gemm1<<<G1_GRID, 256, 0, stream>>>(hbuf, W1, b1);
    k_gemm2<<<G2_GRID, 256, 0, stream>>>(hbuf, W2, dinv, xws_h);
    k_gcn<<<G_NODE, 256, 0, stream>>>(xws_h, dinv, scol, off, cnt, b2, out);
}

// Round 6
// 457.351 us; speedup vs baseline: 1.8261x; 1.1064x over previous
//
#include <hip/hip_runtime.h>
#include <hip/hip_fp16.h>
#include <math.h>

#define N_NODES 100000
#define N_EDGES 1600000
#define F_DIM 128
#define C_DIM 40

#define NBUCK 782            // ceil(100000 / 128) row-buckets of 128 rows
#define EB 4096              // edges per bucket-phase block
#define NBLK_BUCKET ((N_EDGES + EB - 1) / EB)   // 391
#define BCAP 4096            // k_bsort LDS staging capacity (mean bucket ~2046)

typedef unsigned long long ull;

// ---------------- fused prep: LDS bucket histogram + mask pack + x -> premasked fp16 ----------------

#define G_NODE ((N_NODES + 3) / 4)         // 25000 (wave per node)

__global__ __launch_bounds__(256) void k_prep(const int* __restrict__ row,
                                              const int* __restrict__ mask,
                                              const float* __restrict__ x,
                                              int* __restrict__ bcnt,
                                              ull* __restrict__ mbits,
                                              __half* __restrict__ xh) {
    if (blockIdx.x < NBLK_BUCKET) {
        // bucket histogram: 4096 edges per block, 782 LDS bins
        __shared__ int lh[NBUCK];
        int t = threadIdx.x;
        int base = blockIdx.x * EB;
        int cnt = min(EB, N_EDGES - base);
        for (int i = t; i < NBUCK; i += 256) lh[i] = 0;
        __syncthreads();
        for (int i = t; i < cnt; i += 256)
            atomicAdd(&lh[row[base + i] >> 7], 1);
        __syncthreads();
        for (int b = t; b < NBUCK; b += 256) {
            int c = lh[b];
            if (c) atomicAdd(&bcnt[b], c);
        }
        return;
    }
    int nb = blockIdx.x - NBLK_BUCKET;
    int wv = threadIdx.x >> 6;
    int l = threadIdx.x & 63;
    int wid = nb * 4 + wv;                 // < 100000 exactly
    int m0 = mask[wid * F_DIM + l];
    int m1 = mask[wid * F_DIM + 64 + l];
    float x0 = x[wid * F_DIM + l];
    float x1 = x[wid * F_DIM + 64 + l];
    ull b0 = __ballot(m0 != 0);
    ull b1 = __ballot(m1 != 0);
    if (l == 0) {
        mbits[wid * 2 + 0] = b0;
        mbits[wid * 2 + 1] = b1;
    }
    xh[wid * F_DIM + l]      = __float2half(m0 ? x0 : 0.0f);   // premasked
    xh[wid * F_DIM + 64 + l] = __float2half(m1 ? x1 : 0.0f);
}

// ---------------- bucket-count exclusive scan (1 block) ----------------

__global__ __launch_bounds__(256) void k_bscan(const int* __restrict__ bcnt,
                                               int* __restrict__ bbase,
                                               int* __restrict__ bfill) {
    __shared__ int partial[256];
    int t = threadIdx.x;
    int b4 = t * 4;
    int v0 = (b4 + 0 < NBUCK) ? bcnt[b4 + 0] : 0;
    int v1 = (b4 + 1 < NBUCK) ? bcnt[b4 + 1] : 0;
    int v2 = (b4 + 2 < NBUCK) ? bcnt[b4 + 2] : 0;
    int v3 = (b4 + 3 < NBUCK) ? bcnt[b4 + 3] : 0;
    int s0 = v0, s1 = s0 + v1, s2 = s1 + v2, s3 = s2 + v3;
    partial[t] = s3;
    __syncthreads();
    for (int d = 1; d < 256; d <<= 1) {
        int xv = (t >= d) ? partial[t - d] : 0;
        __syncthreads();
        partial[t] += xv;
        __syncthreads();
    }
    int excl = partial[t] - s3;
    if (b4 + 0 < NBUCK) { bbase[b4 + 0] = excl;      bfill[b4 + 0] = excl; }
    if (b4 + 1 < NBUCK) { bbase[b4 + 1] = excl + s0; bfill[b4 + 1] = excl + s0; }
    if (b4 + 2 < NBUCK) { bbase[b4 + 2] = excl + s1; bfill[b4 + 2] = excl + s1; }
    if (b4 + 3 < NBUCK) { bbase[b4 + 3] = excl + s2; bfill[b4 + 3] = excl + s2; }
    if (t == 255) bbase[NBUCK] = partial[255];   // == N_EDGES
}

// ---------------- CSR build phase A: per-block counting sort into coarse buckets ----------------
// Writes packed (col<<32 | row) pairs as contiguous runs into each bucket's region.

__global__ __launch_bounds__(256) void k_bucket(const int* __restrict__ row,
                                                const int* __restrict__ col,
                                                int* __restrict__ bfill,
                                                ull* __restrict__ ebuf) {
    __shared__ int lhist[1024];     // bucket hist, then reused as per-bucket fill
    __shared__ int lscan[1024];
    __shared__ int gbase[NBUCK];
    __shared__ ull stage[EB];       // 32 KB
    __shared__ int partial[256];
    int t = threadIdx.x;
    int base = blockIdx.x * EB;
    int cnt = min(EB, N_EDGES - base);

    for (int i = t; i < 1024; i += 256) lhist[i] = 0;
    __syncthreads();
    for (int i = t; i < cnt; i += 256)
        atomicAdd(&lhist[row[base + i] >> 7], 1);
    __syncthreads();

    int b4 = t * 4;
    int h0 = lhist[b4], h1 = lhist[b4 + 1], h2 = lhist[b4 + 2], h3 = lhist[b4 + 3];
    int s3 = h0 + h1 + h2 + h3;
    partial[t] = s3;
    __syncthreads();
    for (int d = 1; d < 256; d <<= 1) {
        int xv = (t >= d) ? partial[t - d] : 0;
        __syncthreads();
        partial[t] += xv;
        __syncthreads();
    }
    int excl = partial[t] - s3;
    lscan[b4] = excl;
    lscan[b4 + 1] = excl + h0;
    lscan[b4 + 2] = excl + h0 + h1;
    lscan[b4 + 3] = excl + h0 + h1 + h2;
    __syncthreads();

    for (int i = t; i < 1024; i += 256) lhist[i] = 0;   // now per-bucket fill
    __syncthreads();

    for (int i = t; i < cnt; i += 256) {
        int r = row[base + i];
        int c = col[base + i];
        int b = r >> 7;
        int p = lscan[b] + atomicAdd(&lhist[b], 1);
        stage[p] = ((ull)(unsigned)c << 32) | (unsigned)r;
    }
    __syncthreads();

    for (int b = t; b < NBUCK; b += 256) {
        int c = lhist[b];
        gbase[b] = c ? atomicAdd(&bfill[b], c) : 0;
    }
    __syncthreads();

    for (int i = t; i < cnt; i += 256) {
        ull pk = stage[i];
        int b = ((int)(unsigned)(pk & 0xffffffffull)) >> 7;
        int dst = gbase[b] + (i - lscan[b]);
        ebuf[dst] = pk;
    }
}

// ---------------- CSR phase B: in-bucket sort + per-row degree/offset/dinv ----------------

__global__ __launch_bounds__(256) void k_bsort(const ull* __restrict__ ebuf,
                                               const int* __restrict__ bbase,
                                               int* __restrict__ off, int* __restrict__ cnt,
                                               float* __restrict__ dinv,
                                               int* __restrict__ scol) {
    __shared__ ull stage[BCAP];     // 32 KB
    __shared__ int lcol[BCAP];      // 16 KB
    __shared__ int lrc[128];
    __shared__ int lexcl[128];
    __shared__ int lfill[128];
    int b = blockIdx.x;
    int rowbase = b << 7;
    int segstart = bbase[b];
    int m = bbase[b + 1] - segstart;
    int t = threadIdx.x;

    if (t < 128) lrc[t] = 0;
    __syncthreads();
    // load pairs into LDS, count per-row degrees
    for (int i = t; i < m; i += 256) {
        ull pk = ebuf[segstart + i];
        if (i < BCAP) stage[i] = pk;
        atomicAdd(&lrc[(int)(unsigned)(pk & 0xffffffffull) & 127], 1);
    }
    __syncthreads();
    // exclusive scan over 128 row counts (Hillis-Steele in LDS)
    if (t < 128) lexcl[t] = lrc[t];
    __syncthreads();
    for (int d = 1; d < 128; d <<= 1) {
        int xv = (t >= d && t < 128) ? lexcl[t - d] : 0;
        __syncthreads();
        if (t < 128) lexcl[t] += xv;
        __syncthreads();
    }
    if (t < 128) {
        int excl = lexcl[t] - lrc[t];
        lfill[t] = excl;
        int r = rowbase + t;
        if (r < N_NODES) {
            off[r] = segstart + excl;
            cnt[r] = lrc[t];
            dinv[r] = rsqrtf((float)lrc[t] + 1.0f);
        }
        lexcl[t] = excl;   // keep exclusive value
    }
    __syncthreads();
    // scatter cols within LDS to row-grouped order
    for (int i = t; i < m; i += 256) {
        ull pk = (i < BCAP) ? stage[i] : ebuf[segstart + i];
        int r = (int)(unsigned)(pk & 0xffffffffull);
        int c = (int)(unsigned)(pk >> 32);
        int p = atomicAdd(&lfill[r & 127], 1);
        if (p < BCAP) lcol[p] = c;
        else scol[segstart + p] = c;    // essentially never for uniform-random graphs
    }
    __syncthreads();
    int mm = m < BCAP ? m : BCAP;
    for (int i = t; i < mm; i += 256) scol[segstart + i] = lcol[i];
}

// ---------------- PaGNN masked-mean aggregation: wave/node, fp16 premasked gather ----------------

#define AGG_EDGE(W, H, AX, AY, IX, IY)                       \
    {                                                        \
        float2 v = __half22float2(H);                        \
        AX += v.x; AY += v.y;                                \
        IX += (int)((W) >> sh) & 1;                          \
        IY += (int)((W) >> (sh + 1)) & 1;                    \
    }

__global__ __launch_bounds__(256) void k_agg(const __half* __restrict__ xh,
                                             const ull* __restrict__ mbits,
                                             const int* __restrict__ scol,
                                             const int* __restrict__ off, const int* __restrict__ cnt,
                                             float* __restrict__ hbuf) {
    __shared__ int sids[4][64];
    int wv = threadIdx.x >> 6;
    int wid = blockIdx.x * 4 + wv;
    int l = threadIdx.x & 63;
    if (wid >= N_NODES) return;
    int start = off[wid], len = cnt[wid];
    int f = 2 * l;                // this lane owns features f, f+1
    int wsel = l >> 5;
    int sh = f & 63;
    const __half2* xp = (const __half2*)xh;   // index: node*64 + l

    int n = len < 64 ? len : 64;
    sids[wv][l] = (l < n) ? scol[start + l] : 0;

    float ax0 = 0.f, ay0 = 0.f, ax1 = 0.f, ay1 = 0.f;
    float ax2 = 0.f, ay2 = 0.f, ax3 = 0.f, ay3 = 0.f;
    int ix0 = 0, iy0 = 0, ix1 = 0, iy1 = 0;
    int ix2 = 0, iy2 = 0, ix3 = 0, iy3 = 0;

    int j = 0;
    for (; j + 8 <= n; j += 8) {
        int4 ca = *(const int4*)&sids[wv][j];
        int4 cb = *(const int4*)&sids[wv][j + 4];
        ull w0 = mbits[ca.x * 2 + wsel];
        ull w1 = mbits[ca.y * 2 + wsel];
        ull w2 = mbits[ca.z * 2 + wsel];
        ull w3 = mbits[ca.w * 2 + wsel];
        ull w4 = mbits[cb.x * 2 + wsel];
        ull w5 = mbits[cb.y * 2 + wsel];
        ull w6 = mbits[cb.z * 2 + wsel];
        ull w7 = mbits[cb.w * 2 + wsel];
        __half2 h0 = xp[ca.x * 64 + l];
        __half2 h1 = xp[ca.y * 64 + l];
        __half2 h2 = xp[ca.z * 64 + l];
        __half2 h3 = xp[ca.w * 64 + l];
        __half2 h4 = xp[cb.x * 64 + l];
        __half2 h5 = xp[cb.y * 64 + l];
        __half2 h6 = xp[cb.z * 64 + l];
        __half2 h7 = xp[cb.w * 64 + l];
        AGG_EDGE(w0, h0, ax0, ay0, ix0, iy0)
        AGG_EDGE(w1, h1, ax1, ay1, ix1, iy1)
        AGG_EDGE(w2, h2, ax2, ay2, ix2, iy2)
        AGG_EDGE(w3, h3, ax3, ay3, ix3, iy3)
        AGG_EDGE(w4, h4, ax0, ay0, ix0, iy0)
        AGG_EDGE(w5, h5, ax1, ay1, ix1, iy1)
        AGG_EDGE(w6, h6, ax2, ay2, ix2, iy2)
        AGG_EDGE(w7, h7, ax3, ay3, ix3, iy3)
    }
    for (; j + 4 <= n; j += 4) {
        int4 ca = *(const int4*)&sids[wv][j];
        ull w0 = mbits[ca.x * 2 + wsel];
        ull w1 = mbits[ca.y * 2 + wsel];
        ull w2 = mbits[ca.z * 2 + wsel];
        ull w3 = mbits[ca.w * 2 + wsel];
        __half2 h0 = xp[ca.x * 64 + l];
        __half2 h1 = xp[ca.y * 64 + l];
        __half2 h2 = xp[ca.z * 64 + l];
        __half2 h3 = xp[ca.w * 64 + l];
        AGG_EDGE(w0, h0, ax0, ay0, ix0, iy0)
        AGG_EDGE(w1, h1, ax1, ay1, ix1, iy1)
        AGG_EDGE(w2, h2, ax2, ay2, ix2, iy2)
        AGG_EDGE(w3, h3, ax3, ay3, ix3, iy3)
    }
    for (; j < n; j++) {
        int c = sids[wv][j];
        ull w = mbits[c * 2 + wsel];
        __half2 h = xp[c * 64 + l];
        AGG_EDGE(w, h, ax0, ay0, ix0, iy0)
    }
    for (int j2 = 64; j2 < len; j2++) {   // rare tail (degree > 64)
        int c = scol[start + j2];
        ull w = mbits[c * 2 + wsel];
        __half2 h = xp[c * 64 + l];
        AGG_EDGE(w, h, ax0, ay0, ix0, iy0)
    }

    float ax = (ax0 + ax1) + (ax2 + ax3);
    float ay = (ay0 + ay1) + (ay2 + ay3);
    float dx = (float)((ix0 + ix1) + (ix2 + ix3));
    float dy = (float)((iy0 + iy1) + (iy2 + iy3));
    float2 hn;
    hn.x = ax / fmaxf(dx, 1.0f);
    hn.y = ay / fmaxf(dy, 1.0f);
    *(float2*)(hbuf + wid * F_DIM + f) = hn;
}

// ---------------- GEMM1 (persistent): h = relu(hn @ W1 + b1), in-place ----------------

#define G1R 16
#define G1_TILES (N_NODES / G1R)   // 6250
#define G1_GRID 512

__global__ __launch_bounds__(256) void k_gemm1(float* __restrict__ hbuf,
                                               const float* __restrict__ W1,
                                               const float* __restrict__ b1) {
    __shared__ float sW[128 * 128];   // 64 KB, staged ONCE
    __shared__ float srow[G1R * 128]; // 8 KB
    __shared__ float sb[128];
    int t = threadIdx.x;
    for (int i = t; i < 4096; i += 256) ((float4*)sW)[i] = ((const float4*)W1)[i];
    if (t < 128) sb[t] = b1[t];

    int w = t >> 6, l = t & 63;
    int c4 = (l & 31) * 4;
    int rh = l >> 5;
    int r0 = w * 4 + rh * 2;
    const float* srA = &srow[r0 * 128];
    const float* srB = &srow[(r0 + 1) * 128];

    for (int tile = blockIdx.x; tile < G1_TILES; tile += G1_GRID) {
        int rowbase = tile * G1R;
        __syncthreads();   // protect srow from previous iter's readers
        for (int i = t; i < G1R * 128 / 4; i += 256)
            ((float4*)srow)[i] = ((const float4*)(hbuf + rowbase * F_DIM))[i];
        __syncthreads();

        float4 acc0 = {0.f, 0.f, 0.f, 0.f}, acc1 = {0.f, 0.f, 0.f, 0.f};
#pragma unroll 4
        for (int k = 0; k < 128; k++) {
            float4 wv2 = *(const float4*)&sW[k * 128 + c4];
            float a0 = srA[k];
            float a1 = srB[k];
            acc0.x += a0 * wv2.x; acc0.y += a0 * wv2.y; acc0.z += a0 * wv2.z; acc0.w += a0 * wv2.w;
            acc1.x += a1 * wv2.x; acc1.y += a1 * wv2.y; acc1.z += a1 * wv2.z; acc1.w += a1 * wv2.w;
        }
        float4 bb = *(const float4*)&sb[c4];
        float4 o0, o1;
        o0.x = fmaxf(acc0.x + bb.x, 0.f); o0.y = fmaxf(acc0.y + bb.y, 0.f);
        o0.z = fmaxf(acc0.z + bb.z, 0.f); o0.w = fmaxf(acc0.w + bb.w, 0.f);
        o1.x = fmaxf(acc1.x + bb.x, 0.f); o1.y = fmaxf(acc1.y + bb.y, 0.f);
        o1.z = fmaxf(acc1.z + bb.z, 0.f); o1.w = fmaxf(acc1.w + bb.w, 0.f);
        int gr = rowbase + r0;
        *(float4*)&hbuf[gr * F_DIM + c4] = o0;
        *(float4*)&hbuf[(gr + 1) * F_DIM + c4] = o1;
    }
}

// ---------------- GEMM2 (persistent): xws_h = fp16( dinv * (h @ W2) ) ----------------

#define G2R 32
#define G2_TILES (N_NODES / G2R)   // 3125
#define G2_GRID 512

__global__ __launch_bounds__(256) void k_gemm2(const float* __restrict__ hbuf,
                                               const float* __restrict__ W2,
                                               const float* __restrict__ dinv,
                                               __half* __restrict__ xws_h) {
    __shared__ float sW2[128 * 64];   // 32 KB, cols >=40 zero, staged ONCE
    __shared__ float srow[G2R * 128]; // 16 KB
    int t = threadIdx.x;
    for (int i = t; i < 8192; i += 256) {
        int k = i >> 6, c = i & 63;
        sW2[i] = (c < C_DIM) ? W2[k * C_DIM + c] : 0.0f;
    }
    int w = t >> 6, l = t & 63;
    const float* sr = &srow[w * 8 * 128];

    for (int tile = blockIdx.x; tile < G2_TILES; tile += G2_GRID) {
        int rowbase = tile * G2R;
        __syncthreads();
        for (int i = t; i < 1024; i += 256)
            ((float4*)srow)[i] = ((const float4*)(hbuf + rowbase * F_DIM))[i];
        __syncthreads();

        float acc[8] = {0.f, 0.f, 0.f, 0.f, 0.f, 0.f, 0.f, 0.f};
        for (int k = 0; k < 128; k += 4) {
            float w0 = sW2[(k + 0) * 64 + l];
            float w1 = sW2[(k + 1) * 64 + l];
            float w2 = sW2[(k + 2) * 64 + l];
            float w3 = sW2[(k + 3) * 64 + l];
#pragma unroll
            for (int r = 0; r < 8; r++) {
                float4 a = *(const float4*)&sr[r * 128 + k];
                acc[r] += a.x * w0 + a.y * w1 + a.z * w2 + a.w * w3;
            }
        }
        if (l < C_DIM) {
            int grow = rowbase + w * 8;
#pragma unroll
            for (int r = 0; r < 8; r++)
                xws_h[(grow + r) * C_DIM + l] = __float2half(acc[r] * dinv[grow + r]);
        }
    }
}

// ---------------- GCN conv + bias + log_softmax: wave/node, 2 classes/lane fp16 ----------------

__global__ __launch_bounds__(256) void k_gcn(const __half* __restrict__ xws_h,
                                             const float* __restrict__ dinv,
                                             const int* __restrict__ scol,
                                             const int* __restrict__ off, const int* __restrict__ cnt,
                                             const float* __restrict__ b2,
                                             float* __restrict__ out) {
    __shared__ int sids[4][64];
    int wv = threadIdx.x >> 6;
    int wid = blockIdx.x * 4 + wv;
    int l = threadIdx.x & 63;
    if (wid >= N_NODES) return;
    int start = off[wid], len = cnt[wid];
    bool act = l < (C_DIM / 2);           // lanes 0..19 own classes 2l, 2l+1
    int ll = act ? l : 0;
    const __half2* xp = (const __half2*)xws_h;   // index: node*20 + ll

    int n = len < 64 ? len : 64;
    sids[wv][l] = (l < n) ? scol[start + l] : 0;

    float sx0 = 0.f, sy0 = 0.f, sx1 = 0.f, sy1 = 0.f;
    float sx2 = 0.f, sy2 = 0.f, sx3 = 0.f, sy3 = 0.f;
    int j = 0;
    for (; j + 8 <= n; j += 8) {
        int4 ca = *(const int4*)&sids[wv][j];
        int4 cb = *(const int4*)&sids[wv][j + 4];
        float2 t0 = __half22float2(xp[ca.x * 20 + ll]);
        float2 t1 = __half22float2(xp[ca.y * 20 + ll]);
        float2 t2 = __half22float2(xp[ca.z * 20 + ll]);
        float2 t3 = __half22float2(xp[ca.w * 20 + ll]);
        float2 t4 = __half22float2(xp[cb.x * 20 + ll]);
        float2 t5 = __half22float2(xp[cb.y * 20 + ll]);
        float2 t6 = __half22float2(xp[cb.z * 20 + ll]);
        float2 t7 = __half22float2(xp[cb.w * 20 + ll]);
        sx0 += t0.x + t4.x; sy0 += t0.y + t4.y;
        sx1 += t1.x + t5.x; sy1 += t1.y + t5.y;
        sx2 += t2.x + t6.x; sy2 += t2.y + t6.y;
        sx3 += t3.x + t7.x; sy3 += t3.y + t7.y;
    }
    for (; j + 4 <= n; j += 4) {
        int4 ca = *(const int4*)&sids[wv][j];
        float2 t0 = __half22float2(xp[ca.x * 20 + ll]);
        float2 t1 = __half22float2(xp[ca.y * 20 + ll]);
        float2 t2 = __half22float2(xp[ca.z * 20 + ll]);
        float2 t3 = __half22float2(xp[ca.w * 20 + ll]);
        sx0 += t0.x; sy0 += t0.y;
        sx1 += t1.x; sy1 += t1.y;
        sx2 += t2.x; sy2 += t2.y;
        sx3 += t3.x; sy3 += t3.y;
    }
    for (; j < n; j++) {
        float2 t0 = __half22float2(xp[sids[wv][j] * 20 + ll]);
        sx0 += t0.x; sy0 += t0.y;
    }
    for (int j2 = 64; j2 < len; j2++) {
        float2 t0 = __half22float2(xp[scol[start + j2] * 20 + ll]);
        sx0 += t0.x; sy0 += t0.y;
    }

    float di = dinv[wid];
    float2 self = __half22float2(xp[wid * 20 + ll]);
    float sx = (sx0 + sx1) + (sx2 + sx3) + self.x;
    float sy = (sy0 + sy1) + (sy2 + sy3) + self.y;
    float2 bb = act ? ((const float2*)b2)[ll] : make_float2(0.f, 0.f);
    float val0 = di * sx + bb.x;
    float val1 = di * sy + bb.y;

    float m = act ? fmaxf(val0, val1) : -1e30f;
#pragma unroll
    for (int o = 32; o > 0; o >>= 1) m = fmaxf(m, __shfl_xor(m, o, 64));
    float e = act ? (__expf(val0 - m) + __expf(val1 - m)) : 0.0f;
#pragma unroll
    for (int o = 32; o > 0; o >>= 1) e += __shfl_xor(e, o, 64);
    if (act) {
        float lse = m + __logf(e);
        float2 o2 = make_float2(val0 - lse, val1 - lse);
        ((float2*)out)[wid * 20 + l] = o2;
    }
}

// ---------------- launch ----------------

extern "C" void kernel_launch(void* const* d_in, const int* in_sizes, int n_in,
                              void* d_out, int out_size, void* d_ws, size_t ws_size,
                              hipStream_t stream) {
    const float* x = (const float*)d_in[0];
    const int* mask = (const int*)d_in[1];
    const int* eidx = (const int*)d_in[2];
    const float* W1 = (const float*)d_in[3];
    const float* b1 = (const float*)d_in[4];
    const float* W2 = (const float*)d_in[5];
    const float* b2 = (const float*)d_in[6];
    float* out = (float*)d_out;

    const int* row = eidx;
    const int* col = eidx + N_EDGES;

    char* base = (char*)d_ws;
    size_t o = 0;
    auto alloc = [&](size_t bytes) {
        void* p = base + o;
        o = (o + bytes + 255) & ~(size_t)255;
        return p;
    };
    int* cnt = (int*)alloc(N_NODES * 4);
    int* off = (int*)alloc(N_NODES * 4);
    float* dinv = (float*)alloc(N_NODES * 4);
    int* bcnt = (int*)alloc(NBUCK * 4);
    int* bbase = (int*)alloc((NBUCK + 1) * 4);
    int* bfill = (int*)alloc(NBUCK * 4);
    ull* mbits = (ull*)alloc(N_NODES * 16);
    int* scol = (int*)alloc(N_EDGES * 4);
    __half* xh = (__half*)alloc((size_t)N_NODES * F_DIM * 2);
    float* hbuf = (float*)alloc((size_t)N_NODES * F_DIM * 4);
    __half* xws_h = (__half*)alloc((size_t)N_NODES * C_DIM * 2);
    (void)ws_size;

    ull* ebuf = (ull*)hbuf;   // alias: ebuf dead before k_agg writes hbuf (12.8 MB <= 51.2 MB)

    hipMemsetAsync(bcnt, 0, NBUCK * 4, stream);

    k_prep<<<NBLK_BUCKET + G_NODE, 256, 0, stream>>>(row, mask, x, bcnt, mbits, xh);
    k_bscan<<<1, 256, 0, stream>>>(bcnt, bbase, bfill);
    k_bucket<<<NBLK_BUCKET, 256, 0, stream>>>(row, col, bfill, ebuf);
    k_bsort<<<NBUCK, 256, 0, stream>>>(ebuf, bbase, off, cnt, dinv, scol);
    k_agg<<<G_NODE, 256, 0, stream>>>(xh, mbits, scol, off, cnt, hbuf);
    k_gemm1<<<G1_GRID, 256, 0, stream>>>(hbuf, W1, b1);
    k_gemm2<<<G2_GRID, 256, 0, stream>>>(hbuf, W2, dinv, xws_h);
    k_gcn<<<G_NODE, 256, 0, stream>>>(xws_h, dinv, scol, off, cnt, b2, out);
}

// Round 7
// 334.122 us; speedup vs baseline: 2.4996x; 1.3688x over previous
//
#include <hip/hip_runtime.h>
#include <hip/hip_fp16.h>
#include <math.h>

#define N_NODES 100000
#define N_EDGES 1600000
#define F_DIM 128
#define C_DIM 40

#define NBUCK 782            // ceil(100000 / 128) row-buckets of 128 rows
#define EB 4096              // edges per bucket-phase block
#define NBLK_BUCKET ((N_EDGES + EB - 1) / EB)   // 391
#define BCAP 4096            // k_bsort LDS staging capacity (mean bucket ~2046)

typedef unsigned long long ull;
typedef unsigned int uint;
typedef unsigned short ushort;

typedef __attribute__((ext_vector_type(8))) short bf16x8;
typedef __attribute__((ext_vector_type(4))) float f32x4;

__device__ __forceinline__ ushort f2bf(float f) {   // fp32 -> bf16 bits, RNE
    uint u = __float_as_uint(f);
    uint r = u + 0x7FFFu + ((u >> 16) & 1u);
    return (ushort)(r >> 16);
}

// ---------------- fused prep: LDS bucket histogram + x -> premasked nonzero-encoded fp16 ----------------
// Encoding: masked-out -> 0x0000 exactly; observed -> fp16(x), with +0.0 forced to
// minimal subnormal (6e-8) so "observed" <=> bits != 0. (-0.0 is 0x8000, already nonzero.)

#define G_NODE ((N_NODES + 3) / 4)         // 25000 (wave per node)

__global__ __launch_bounds__(256) void k_prep(const int* __restrict__ row,
                                              const int* __restrict__ mask,
                                              const float* __restrict__ x,
                                              int* __restrict__ bcnt,
                                              __half* __restrict__ xh) {
    if (blockIdx.x < NBLK_BUCKET) {
        __shared__ int lh[NBUCK];
        int t = threadIdx.x;
        int base = blockIdx.x * EB;
        int cnt = min(EB, N_EDGES - base);
        for (int i = t; i < NBUCK; i += 256) lh[i] = 0;
        __syncthreads();
        for (int i = t; i < cnt; i += 256)
            atomicAdd(&lh[row[base + i] >> 7], 1);
        __syncthreads();
        for (int b = t; b < NBUCK; b += 256) {
            int c = lh[b];
            if (c) atomicAdd(&bcnt[b], c);
        }
        return;
    }
    int nb = blockIdx.x - NBLK_BUCKET;
    int wv = threadIdx.x >> 6;
    int l = threadIdx.x & 63;
    int wid = nb * 4 + wv;                 // < 100000 exactly
    int m0 = mask[wid * F_DIM + l];
    int m1 = mask[wid * F_DIM + 64 + l];
    float x0 = x[wid * F_DIM + l];
    float x1 = x[wid * F_DIM + 64 + l];
    ushort e0 = 0, e1 = 0;
    if (m0) { e0 = __half_as_ushort(__float2half(x0)); if (e0 == 0) e0 = 1; }
    if (m1) { e1 = __half_as_ushort(__float2half(x1)); if (e1 == 0) e1 = 1; }
    ((ushort*)xh)[wid * F_DIM + l]      = e0;
    ((ushort*)xh)[wid * F_DIM + 64 + l] = e1;
}

// ---------------- bucket-count exclusive scan (1 block) ----------------

__global__ __launch_bounds__(256) void k_bscan(const int* __restrict__ bcnt,
                                               int* __restrict__ bbase,
                                               int* __restrict__ bfill) {
    __shared__ int partial[256];
    int t = threadIdx.x;
    int b4 = t * 4;
    int v0 = (b4 + 0 < NBUCK) ? bcnt[b4 + 0] : 0;
    int v1 = (b4 + 1 < NBUCK) ? bcnt[b4 + 1] : 0;
    int v2 = (b4 + 2 < NBUCK) ? bcnt[b4 + 2] : 0;
    int v3 = (b4 + 3 < NBUCK) ? bcnt[b4 + 3] : 0;
    int s0 = v0, s1 = s0 + v1, s2 = s1 + v2, s3 = s2 + v3;
    partial[t] = s3;
    __syncthreads();
    for (int d = 1; d < 256; d <<= 1) {
        int xv = (t >= d) ? partial[t - d] : 0;
        __syncthreads();
        partial[t] += xv;
        __syncthreads();
    }
    int excl = partial[t] - s3;
    if (b4 + 0 < NBUCK) { bbase[b4 + 0] = excl;      bfill[b4 + 0] = excl; }
    if (b4 + 1 < NBUCK) { bbase[b4 + 1] = excl + s0; bfill[b4 + 1] = excl + s0; }
    if (b4 + 2 < NBUCK) { bbase[b4 + 2] = excl + s1; bfill[b4 + 2] = excl + s1; }
    if (b4 + 3 < NBUCK) { bbase[b4 + 3] = excl + s2; bfill[b4 + 3] = excl + s2; }
    if (t == 255) bbase[NBUCK] = partial[255];   // == N_EDGES
}

// ---------------- CSR build phase A: per-block counting sort into coarse buckets ----------------

__global__ __launch_bounds__(256) void k_bucket(const int* __restrict__ row,
                                                const int* __restrict__ col,
                                                int* __restrict__ bfill,
                                                ull* __restrict__ ebuf) {
    __shared__ int lhist[1024];
    __shared__ int lscan[1024];
    __shared__ int gbase[NBUCK];
    __shared__ ull stage[EB];       // 32 KB
    __shared__ int partial[256];
    int t = threadIdx.x;
    int base = blockIdx.x * EB;
    int cnt = min(EB, N_EDGES - base);

    for (int i = t; i < 1024; i += 256) lhist[i] = 0;
    __syncthreads();
    for (int i = t; i < cnt; i += 256)
        atomicAdd(&lhist[row[base + i] >> 7], 1);
    __syncthreads();

    int b4 = t * 4;
    int h0 = lhist[b4], h1 = lhist[b4 + 1], h2 = lhist[b4 + 2], h3 = lhist[b4 + 3];
    int s3 = h0 + h1 + h2 + h3;
    partial[t] = s3;
    __syncthreads();
    for (int d = 1; d < 256; d <<= 1) {
        int xv = (t >= d) ? partial[t - d] : 0;
        __syncthreads();
        partial[t] += xv;
        __syncthreads();
    }
    int excl = partial[t] - s3;
    lscan[b4] = excl;
    lscan[b4 + 1] = excl + h0;
    lscan[b4 + 2] = excl + h0 + h1;
    lscan[b4 + 3] = excl + h0 + h1 + h2;
    __syncthreads();

    for (int i = t; i < 1024; i += 256) lhist[i] = 0;
    __syncthreads();

    for (int i = t; i < cnt; i += 256) {
        int r = row[base + i];
        int c = col[base + i];
        int b = r >> 7;
        int p = lscan[b] + atomicAdd(&lhist[b], 1);
        stage[p] = ((ull)(unsigned)c << 32) | (unsigned)r;
    }
    __syncthreads();

    for (int b = t; b < NBUCK; b += 256) {
        int c = lhist[b];
        gbase[b] = c ? atomicAdd(&bfill[b], c) : 0;
    }
    __syncthreads();

    for (int i = t; i < cnt; i += 256) {
        ull pk = stage[i];
        int b = ((int)(unsigned)(pk & 0xffffffffull)) >> 7;
        int dst = gbase[b] + (i - lscan[b]);
        ebuf[dst] = pk;
    }
}

// ---------------- CSR phase B: in-bucket sort + per-row degree/offset/dinv ----------------

__global__ __launch_bounds__(256) void k_bsort(const ull* __restrict__ ebuf,
                                               const int* __restrict__ bbase,
                                               int* __restrict__ off, int* __restrict__ cnt,
                                               float* __restrict__ dinv,
                                               int* __restrict__ scol) {
    __shared__ ull stage[BCAP];     // 32 KB
    __shared__ int lcol[BCAP];      // 16 KB
    __shared__ int lrc[128];
    __shared__ int lexcl[128];
    __shared__ int lfill[128];
    int b = blockIdx.x;
    int rowbase = b << 7;
    int segstart = bbase[b];
    int m = bbase[b + 1] - segstart;
    int t = threadIdx.x;

    if (t < 128) lrc[t] = 0;
    __syncthreads();
    for (int i = t; i < m; i += 256) {
        ull pk = ebuf[segstart + i];
        if (i < BCAP) stage[i] = pk;
        atomicAdd(&lrc[(int)(unsigned)(pk & 0xffffffffull) & 127], 1);
    }
    __syncthreads();
    if (t < 128) lexcl[t] = lrc[t];
    __syncthreads();
    for (int d = 1; d < 128; d <<= 1) {
        int xv = (t >= d && t < 128) ? lexcl[t - d] : 0;
        __syncthreads();
        if (t < 128) lexcl[t] += xv;
        __syncthreads();
    }
    if (t < 128) {
        int excl = lexcl[t] - lrc[t];
        lfill[t] = excl;
        int r = rowbase + t;
        if (r < N_NODES) {
            off[r] = segstart + excl;
            cnt[r] = lrc[t];
            dinv[r] = rsqrtf((float)lrc[t] + 1.0f);
        }
    }
    __syncthreads();
    for (int i = t; i < m; i += 256) {
        ull pk = (i < BCAP) ? stage[i] : ebuf[segstart + i];
        int r = (int)(unsigned)(pk & 0xffffffffull);
        int c = (int)(unsigned)(pk >> 32);
        int p = atomicAdd(&lfill[r & 127], 1);
        if (p < BCAP) lcol[p] = c;
        else scol[segstart + p] = c;
    }
    __syncthreads();
    int mm = m < BCAP ? m : BCAP;
    for (int i = t; i < mm; i += 256) scol[segstart + i] = lcol[i];
}

// ---------------- PaGNN masked-mean aggregation: wave/node, single nonzero-encoded gather ----------------
// deg = count of nonzero fp16 bit patterns; output hn as bf16 pair per lane.

__device__ __forceinline__ void agg_one(uint u, float& ax, float& ay, int& ix, int& iy) {
    float2 v = __half22float2(*reinterpret_cast<__half2*>(&u));
    ax += v.x; ay += v.y;
    ix += (u & 0xffffu) ? 1 : 0;
    iy += (u >> 16) ? 1 : 0;
}

__global__ __launch_bounds__(256) void k_agg(const __half* __restrict__ xh,
                                             const int* __restrict__ scol,
                                             const int* __restrict__ off, const int* __restrict__ cnt,
                                             uint* __restrict__ hb16) {
    __shared__ int sids[4][64];
    int wv = threadIdx.x >> 6;
    int wid = blockIdx.x * 4 + wv;
    int l = threadIdx.x & 63;
    if (wid >= N_NODES) return;
    int start = off[wid], len = cnt[wid];
    const uint* xu = (const uint*)xh;   // index: node*64 + l  (features 2l, 2l+1)

    int n = len < 64 ? len : 64;
    sids[wv][l] = (l < n) ? scol[start + l] : 0;

    float ax0 = 0.f, ay0 = 0.f, ax1 = 0.f, ay1 = 0.f;
    float ax2 = 0.f, ay2 = 0.f, ax3 = 0.f, ay3 = 0.f;
    int ix0 = 0, iy0 = 0, ix1 = 0, iy1 = 0;
    int ix2 = 0, iy2 = 0, ix3 = 0, iy3 = 0;

    int j = 0;
    for (; j + 8 <= n; j += 8) {
        int4 ca = *(const int4*)&sids[wv][j];
        int4 cb = *(const int4*)&sids[wv][j + 4];
        uint u0 = xu[ca.x * 64 + l];
        uint u1 = xu[ca.y * 64 + l];
        uint u2 = xu[ca.z * 64 + l];
        uint u3 = xu[ca.w * 64 + l];
        uint u4 = xu[cb.x * 64 + l];
        uint u5 = xu[cb.y * 64 + l];
        uint u6 = xu[cb.z * 64 + l];
        uint u7 = xu[cb.w * 64 + l];
        agg_one(u0, ax0, ay0, ix0, iy0);
        agg_one(u1, ax1, ay1, ix1, iy1);
        agg_one(u2, ax2, ay2, ix2, iy2);
        agg_one(u3, ax3, ay3, ix3, iy3);
        agg_one(u4, ax0, ay0, ix0, iy0);
        agg_one(u5, ax1, ay1, ix1, iy1);
        agg_one(u6, ax2, ay2, ix2, iy2);
        agg_one(u7, ax3, ay3, ix3, iy3);
    }
    for (; j + 4 <= n; j += 4) {
        int4 ca = *(const int4*)&sids[wv][j];
        uint u0 = xu[ca.x * 64 + l];
        uint u1 = xu[ca.y * 64 + l];
        uint u2 = xu[ca.z * 64 + l];
        uint u3 = xu[ca.w * 64 + l];
        agg_one(u0, ax0, ay0, ix0, iy0);
        agg_one(u1, ax1, ay1, ix1, iy1);
        agg_one(u2, ax2, ay2, ix2, iy2);
        agg_one(u3, ax3, ay3, ix3, iy3);
    }
    for (; j < n; j++) {
        uint u = xu[sids[wv][j] * 64 + l];
        agg_one(u, ax0, ay0, ix0, iy0);
    }
    for (int j2 = 64; j2 < len; j2++) {   // rare tail (degree > 64)
        uint u = xu[scol[start + j2] * 64 + l];
        agg_one(u, ax0, ay0, ix0, iy0);
    }

    float ax = (ax0 + ax1) + (ax2 + ax3);
    float ay = (ay0 + ay1) + (ay2 + ay3);
    float dx = (float)((ix0 + ix1) + (ix2 + ix3));
    float dy = (float)((iy0 + iy1) + (iy2 + iy3));
    float hx = ax / fmaxf(dx, 1.0f);
    float hy = ay / fmaxf(dy, 1.0f);
    hb16[wid * 64 + l] = (uint)f2bf(hx) | ((uint)f2bf(hy) << 16);
}

// ---------------- fused MLP (persistent MFMA): xws_h = fp16( dinv * relu(hn@W1+b1) @ W2 ) ----------------
// 64-row tiles; wave wv owns rows wv*16..wv*16+15 (wave-private through both GEMMs).
// MFMA 16x16x32 bf16. A layout: A[m=lane&15][k=quad*8+j]; B: B[k=quad*8+j][n=lane&15];
// C/D: col=lane&15, row=quad*4+reg.

#define MLP_TILES ((N_NODES + 63) / 64)   // 1563
#define MLP_GRID 512
#define LDW 136                            // padded row stride (bf16) -> 2-way banks, free

__global__ __launch_bounds__(256) void k_mlp(const uint* __restrict__ hb16,
                                             const float* __restrict__ W1,
                                             const float* __restrict__ b1,
                                             const float* __restrict__ W2,
                                             const float* __restrict__ dinv,
                                             __half* __restrict__ xws_h) {
    __shared__ ushort sW1T[128 * LDW];   // W1^T bf16: [n][k], 34 KB
    __shared__ ushort sW2T[48 * LDW];    // W2^T bf16: [n][k], cols 40..47 zero, 12.75 KB
    __shared__ ushort sA[64 * LDW];      // hn tile / then h tile, 17 KB
    __shared__ float sb1[128];
    int t = threadIdx.x;

    for (int i = t; i < 128 * 128; i += 256) {
        int k = i >> 7, nn = i & 127;
        sW1T[nn * LDW + k] = f2bf(W1[i]);
    }
    for (int i = t; i < 48 * LDW; i += 256) sW2T[i] = 0;
    if (t < 128) sb1[t] = b1[t];
    __syncthreads();
    for (int i = t; i < 128 * C_DIM; i += 256) {
        int k = i / C_DIM, nn = i - k * C_DIM;
        sW2T[nn * LDW + k] = f2bf(W2[i]);
    }

    int wv = t >> 6, l = t & 63;
    int lr = l & 15, quad = l >> 4;

    for (int tile = blockIdx.x; tile < MLP_TILES; tile += MLP_GRID) {
        int rowbase = tile * 64;
        __syncthreads();   // protect sA from previous iteration readers
        // stage 64 rows of hn (bf16) -> sA
        for (int i = t; i < 1024; i += 256) {
            int r = i >> 4, c = i & 15;     // c: uint4 index within row (16 B = 8 bf16)
            uint4 v = make_uint4(0, 0, 0, 0);
            if (rowbase + r < N_NODES)
                v = ((const uint4*)hb16)[(size_t)(rowbase + r) * 16 + c];
            *(uint4*)&sA[r * LDW + c * 8] = v;
        }
        __syncthreads();

        // ---- GEMM1: h = relu(hn @ W1 + b1), stay in this wave's 16 rows ----
        bf16x8 af[4];
#pragma unroll
        for (int kk = 0; kk < 4; kk++)
            af[kk] = *(const bf16x8*)&sA[(wv * 16 + lr) * LDW + kk * 32 + quad * 8];

        f32x4 acc[8];
#pragma unroll
        for (int ct = 0; ct < 8; ct++) {
            acc[ct] = (f32x4){0.f, 0.f, 0.f, 0.f};
#pragma unroll
            for (int kk = 0; kk < 4; kk++) {
                bf16x8 bf = *(const bf16x8*)&sW1T[(ct * 16 + lr) * LDW + kk * 32 + quad * 8];
                acc[ct] = __builtin_amdgcn_mfma_f32_16x16x32_bf16(af[kk], bf, acc[ct], 0, 0, 0);
            }
        }
        // bias + relu, store h (bf16) back into this wave's rows of sA
#pragma unroll
        for (int ct = 0; ct < 8; ct++) {
            float bb = sb1[ct * 16 + lr];
#pragma unroll
            for (int r = 0; r < 4; r++) {
                float hv = fmaxf(acc[ct][r] + bb, 0.0f);
                sA[(wv * 16 + quad * 4 + r) * LDW + ct * 16 + lr] = f2bf(hv);
            }
        }
        // ---- GEMM2: xws = dinv * (h @ W2) ---- (same wave's rows: LDS in-order, no barrier)
        bf16x8 hf[4];
#pragma unroll
        for (int kk = 0; kk < 4; kk++)
            hf[kk] = *(const bf16x8*)&sA[(wv * 16 + lr) * LDW + kk * 32 + quad * 8];

        float dv[4];
#pragma unroll
        for (int r = 0; r < 4; r++) {
            int grow = rowbase + wv * 16 + quad * 4 + r;
            dv[r] = (grow < N_NODES) ? dinv[grow] : 0.0f;
        }
#pragma unroll
        for (int ct2 = 0; ct2 < 3; ct2++) {
            f32x4 acc2 = (f32x4){0.f, 0.f, 0.f, 0.f};
#pragma unroll
            for (int kk = 0; kk < 4; kk++) {
                bf16x8 bf = *(const bf16x8*)&sW2T[(ct2 * 16 + lr) * LDW + kk * 32 + quad * 8];
                acc2 = __builtin_amdgcn_mfma_f32_16x16x32_bf16(hf[kk], bf, acc2, 0, 0, 0);
            }
            int nn = ct2 * 16 + lr;
            if (nn < C_DIM) {
#pragma unroll
                for (int r = 0; r < 4; r++) {
                    int grow = rowbase + wv * 16 + quad * 4 + r;
                    if (grow < N_NODES)
                        xws_h[(size_t)grow * C_DIM + nn] = __float2half(acc2[r] * dv[r]);
                }
            }
        }
    }
}

// ---------------- GCN conv + bias + log_softmax: wave/node, 2 classes/lane fp16 ----------------

__global__ __launch_bounds__(256) void k_gcn(const __half* __restrict__ xws_h,
                                             const float* __restrict__ dinv,
                                             const int* __restrict__ scol,
                                             const int* __restrict__ off, const int* __restrict__ cnt,
                                             const float* __restrict__ b2,
                                             float* __restrict__ out) {
    __shared__ int sids[4][64];
    int wv = threadIdx.x >> 6;
    int wid = blockIdx.x * 4 + wv;
    int l = threadIdx.x & 63;
    if (wid >= N_NODES) return;
    int start = off[wid], len = cnt[wid];
    bool act = l < (C_DIM / 2);           // lanes 0..19 own classes 2l, 2l+1
    int ll = act ? l : 0;
    const __half2* xp = (const __half2*)xws_h;   // index: node*20 + ll

    int n = len < 64 ? len : 64;
    sids[wv][l] = (l < n) ? scol[start + l] : 0;

    float sx0 = 0.f, sy0 = 0.f, sx1 = 0.f, sy1 = 0.f;
    float sx2 = 0.f, sy2 = 0.f, sx3 = 0.f, sy3 = 0.f;
    int j = 0;
    for (; j + 8 <= n; j += 8) {
        int4 ca = *(const int4*)&sids[wv][j];
        int4 cb = *(const int4*)&sids[wv][j + 4];
        float2 t0 = __half22float2(xp[ca.x * 20 + ll]);
        float2 t1 = __half22float2(xp[ca.y * 20 + ll]);
        float2 t2 = __half22float2(xp[ca.z * 20 + ll]);
        float2 t3 = __half22float2(xp[ca.w * 20 + ll]);
        float2 t4 = __half22float2(xp[cb.x * 20 + ll]);
        float2 t5 = __half22float2(xp[cb.y * 20 + ll]);
        float2 t6 = __half22float2(xp[cb.z * 20 + ll]);
        float2 t7 = __half22float2(xp[cb.w * 20 + ll]);
        sx0 += t0.x + t4.x; sy0 += t0.y + t4.y;
        sx1 += t1.x + t5.x; sy1 += t1.y + t5.y;
        sx2 += t2.x + t6.x; sy2 += t2.y + t6.y;
        sx3 += t3.x + t7.x; sy3 += t3.y + t7.y;
    }
    for (; j + 4 <= n; j += 4) {
        int4 ca = *(const int4*)&sids[wv][j];
        float2 t0 = __half22float2(xp[ca.x * 20 + ll]);
        float2 t1 = __half22float2(xp[ca.y * 20 + ll]);
        float2 t2 = __half22float2(xp[ca.z * 20 + ll]);
        float2 t3 = __half22float2(xp[ca.w * 20 + ll]);
        sx0 += t0.x; sy0 += t0.y;
        sx1 += t1.x; sy1 += t1.y;
        sx2 += t2.x; sy2 += t2.y;
        sx3 += t3.x; sy3 += t3.y;
    }
    for (; j < n; j++) {
        float2 t0 = __half22float2(xp[sids[wv][j] * 20 + ll]);
        sx0 += t0.x; sy0 += t0.y;
    }
    for (int j2 = 64; j2 < len; j2++) {
        float2 t0 = __half22float2(xp[scol[start + j2] * 20 + ll]);
        sx0 += t0.x; sy0 += t0.y;
    }

    float di = dinv[wid];
    float2 self = __half22float2(xp[wid * 20 + ll]);
    float sx = (sx0 + sx1) + (sx2 + sx3) + self.x;
    float sy = (sy0 + sy1) + (sy2 + sy3) + self.y;
    float2 bb = act ? ((const float2*)b2)[ll] : make_float2(0.f, 0.f);
    float val0 = di * sx + bb.x;
    float val1 = di * sy + bb.y;

    float m = act ? fmaxf(val0, val1) : -1e30f;
#pragma unroll
    for (int o = 32; o > 0; o >>= 1) m = fmaxf(m, __shfl_xor(m, o, 64));
    float e = act ? (__expf(val0 - m) + __expf(val1 - m)) : 0.0f;
#pragma unroll
    for (int o = 32; o > 0; o >>= 1) e += __shfl_xor(e, o, 64);
    if (act) {
        float lse = m + __logf(e);
        float2 o2 = make_float2(val0 - lse, val1 - lse);
        ((float2*)out)[wid * 20 + l] = o2;
    }
}

// ---------------- launch ----------------

extern "C" void kernel_launch(void* const* d_in, const int* in_sizes, int n_in,
                              void* d_out, int out_size, void* d_ws, size_t ws_size,
                              hipStream_t stream) {
    const float* x = (const float*)d_in[0];
    const int* mask = (const int*)d_in[1];
    const int* eidx = (const int*)d_in[2];
    const float* W1 = (const float*)d_in[3];
    const float* b1 = (const float*)d_in[4];
    const float* W2 = (const float*)d_in[5];
    const float* b2 = (const float*)d_in[6];
    float* out = (float*)d_out;

    const int* row = eidx;
    const int* col = eidx + N_EDGES;

    char* base = (char*)d_ws;
    size_t o = 0;
    auto alloc = [&](size_t bytes) {
        void* p = base + o;
        o = (o + bytes + 255) & ~(size_t)255;
        return p;
    };
    int* cnt = (int*)alloc(N_NODES * 4);
    int* off = (int*)alloc(N_NODES * 4);
    float* dinv = (float*)alloc(N_NODES * 4);
    int* bcnt = (int*)alloc(NBUCK * 4);
    int* bbase = (int*)alloc((NBUCK + 1) * 4);
    int* bfill = (int*)alloc(NBUCK * 4);
    int* scol = (int*)alloc(N_EDGES * 4);
    __half* xh = (__half*)alloc((size_t)N_NODES * F_DIM * 2);
    uint* hb16 = (uint*)alloc((size_t)N_NODES * F_DIM * 2);   // hn as bf16 (uint-packed pairs)
    __half* xws_h = (__half*)alloc((size_t)N_NODES * C_DIM * 2);
    (void)ws_size;

    ull* ebuf = (ull*)hb16;   // alias: ebuf (12.8 MB) dead before k_agg writes hb16 (25.6 MB)

    hipMemsetAsync(bcnt, 0, NBUCK * 4, stream);

    k_prep<<<NBLK_BUCKET + G_NODE, 256, 0, stream>>>(row, mask, x, bcnt, xh);
    k_bscan<<<1, 256, 0, stream>>>(bcnt, bbase, bfill);
    k_bucket<<<NBLK_BUCKET, 256, 0, stream>>>(row, col, bfill, ebuf);
    k_bsort<<<NBUCK, 256, 0, stream>>>(ebuf, bbase, off, cnt, dinv, scol);
    k_agg<<<G_NODE, 256, 0, stream>>>(xh, scol, off, cnt, hb16);
    k_mlp<<<MLP_GRID, 256, 0, stream>>>(hb16, W1, b1, W2, dinv, xws_h);
    k_gcn<<<G_NODE, 256, 0, stream>>>(xws_h, dinv, scol, off, cnt, b2, out);
}

// Round 8
// 326.640 us; speedup vs baseline: 2.5569x; 1.0229x over previous
//
#include <hip/hip_runtime.h>
#include <hip/hip_fp16.h>
#include <math.h>

#define N_NODES 100000
#define N_EDGES 1600000
#define F_DIM 128
#define C_DIM 40

#define NBUCK 782            // ceil(100000 / 128) row-buckets of 128 rows
#define EB 4096              // edges per bucket-phase block
#define NBLK_BUCKET ((N_EDGES + EB - 1) / EB)   // 391
#define BCAP 4096            // k_bsort LDS staging capacity (mean bucket ~2046)

typedef unsigned long long ull;
typedef unsigned int uint;
typedef unsigned short ushort;

typedef __attribute__((ext_vector_type(8))) short bf16x8;
typedef __attribute__((ext_vector_type(4))) float f32x4;

__device__ __forceinline__ ushort f2bf(float f) {   // fp32 -> bf16 bits, RNE
    uint u = __float_as_uint(f);
    uint r = u + 0x7FFFu + ((u >> 16) & 1u);
    return (ushort)(r >> 16);
}

// fp16-pair accumulate: ax += h.x, ay += h.y (fp32 accumulation)
#if __has_builtin(__builtin_amdgcn_fdot2)
typedef __attribute__((ext_vector_type(2))) _Float16 h2f;
__device__ __forceinline__ void acc_xy(uint u, float& ax, float& ay) {
    union { uint u; h2f h; } z; z.u = u;
    union { uint u; h2f h; } ox; ox.u = 0x00003C00u;   // (1.0h, 0.0h)
    union { uint u; h2f h; } oy; oy.u = 0x3C000000u;   // (0.0h, 1.0h)
    ax = __builtin_amdgcn_fdot2(z.h, ox.h, ax, false);
    ay = __builtin_amdgcn_fdot2(z.h, oy.h, ay, false);
}
#else
__device__ __forceinline__ void acc_xy(uint u, float& ax, float& ay) {
    float2 v = __half22float2(*reinterpret_cast<__half2*>(&u));
    ax += v.x; ay += v.y;
}
#endif

__device__ __forceinline__ void cnt_xy(uint u, int& ix, int& iy) {
    ix += (u & 0xffffu) ? 1 : 0;
    iy += (u >> 16) ? 1 : 0;
}

#define RFL(v) __builtin_amdgcn_readfirstlane(v)

// ---------------- fused prep: LDS bucket histogram + x -> premasked nonzero-encoded fp16 ----------------
// Encoding: masked-out -> 0x0000 exactly; observed -> fp16(x), with +0.0 forced to
// minimal subnormal (6e-8) so "observed" <=> bits != 0. (-0.0 is 0x8000, already nonzero.)

#define G_NODE ((N_NODES + 3) / 4)         // 25000 (wave per node)

__global__ __launch_bounds__(256) void k_prep(const int* __restrict__ row,
                                              const int* __restrict__ mask,
                                              const float* __restrict__ x,
                                              int* __restrict__ bcnt,
                                              __half* __restrict__ xh) {
    if (blockIdx.x < NBLK_BUCKET) {
        __shared__ int lh[NBUCK];
        int t = threadIdx.x;
        int base = blockIdx.x * EB;
        int cnt = min(EB, N_EDGES - base);
        for (int i = t; i < NBUCK; i += 256) lh[i] = 0;
        __syncthreads();
        for (int i = t; i < cnt; i += 256)
            atomicAdd(&lh[row[base + i] >> 7], 1);
        __syncthreads();
        for (int b = t; b < NBUCK; b += 256) {
            int c = lh[b];
            if (c) atomicAdd(&bcnt[b], c);
        }
        return;
    }
    int nb = blockIdx.x - NBLK_BUCKET;
    int wv = threadIdx.x >> 6;
    int l = threadIdx.x & 63;
    int wid = nb * 4 + wv;                 // < 100000 exactly
    int m0 = mask[wid * F_DIM + l];
    int m1 = mask[wid * F_DIM + 64 + l];
    float x0 = x[wid * F_DIM + l];
    float x1 = x[wid * F_DIM + 64 + l];
    ushort e0 = 0, e1 = 0;
    if (m0) { e0 = __half_as_ushort(__float2half(x0)); if (e0 == 0) e0 = 1; }
    if (m1) { e1 = __half_as_ushort(__float2half(x1)); if (e1 == 0) e1 = 1; }
    ((ushort*)xh)[wid * F_DIM + l]      = e0;
    ((ushort*)xh)[wid * F_DIM + 64 + l] = e1;
}

// ---------------- bucket-count exclusive scan (1 block) ----------------

__global__ __launch_bounds__(256) void k_bscan(const int* __restrict__ bcnt,
                                               int* __restrict__ bbase,
                                               int* __restrict__ bfill) {
    __shared__ int partial[256];
    int t = threadIdx.x;
    int b4 = t * 4;
    int v0 = (b4 + 0 < NBUCK) ? bcnt[b4 + 0] : 0;
    int v1 = (b4 + 1 < NBUCK) ? bcnt[b4 + 1] : 0;
    int v2 = (b4 + 2 < NBUCK) ? bcnt[b4 + 2] : 0;
    int v3 = (b4 + 3 < NBUCK) ? bcnt[b4 + 3] : 0;
    int s0 = v0, s1 = s0 + v1, s2 = s1 + v2, s3 = s2 + v3;
    partial[t] = s3;
    __syncthreads();
    for (int d = 1; d < 256; d <<= 1) {
        int xv = (t >= d) ? partial[t - d] : 0;
        __syncthreads();
        partial[t] += xv;
        __syncthreads();
    }
    int excl = partial[t] - s3;
    if (b4 + 0 < NBUCK) { bbase[b4 + 0] = excl;      bfill[b4 + 0] = excl; }
    if (b4 + 1 < NBUCK) { bbase[b4 + 1] = excl + s0; bfill[b4 + 1] = excl + s0; }
    if (b4 + 2 < NBUCK) { bbase[b4 + 2] = excl + s1; bfill[b4 + 2] = excl + s1; }
    if (b4 + 3 < NBUCK) { bbase[b4 + 3] = excl + s2; bfill[b4 + 3] = excl + s2; }
    if (t == 255) bbase[NBUCK] = partial[255];   // == N_EDGES
}

// ---------------- CSR build phase A: per-block counting sort into coarse buckets ----------------

__global__ __launch_bounds__(256) void k_bucket(const int* __restrict__ row,
                                                const int* __restrict__ col,
                                                int* __restrict__ bfill,
                                                ull* __restrict__ ebuf) {
    __shared__ int lhist[1024];
    __shared__ int lscan[1024];
    __shared__ int gbase[NBUCK];
    __shared__ ull stage[EB];       // 32 KB
    __shared__ int partial[256];
    int t = threadIdx.x;
    int base = blockIdx.x * EB;
    int cnt = min(EB, N_EDGES - base);

    for (int i = t; i < 1024; i += 256) lhist[i] = 0;
    __syncthreads();
    for (int i = t; i < cnt; i += 256)
        atomicAdd(&lhist[row[base + i] >> 7], 1);
    __syncthreads();

    int b4 = t * 4;
    int h0 = lhist[b4], h1 = lhist[b4 + 1], h2 = lhist[b4 + 2], h3 = lhist[b4 + 3];
    int s3 = h0 + h1 + h2 + h3;
    partial[t] = s3;
    __syncthreads();
    for (int d = 1; d < 256; d <<= 1) {
        int xv = (t >= d) ? partial[t - d] : 0;
        __syncthreads();
        partial[t] += xv;
        __syncthreads();
    }
    int excl = partial[t] - s3;
    lscan[b4] = excl;
    lscan[b4 + 1] = excl + h0;
    lscan[b4 + 2] = excl + h0 + h1;
    lscan[b4 + 3] = excl + h0 + h1 + h2;
    __syncthreads();

    for (int i = t; i < 1024; i += 256) lhist[i] = 0;
    __syncthreads();

    for (int i = t; i < cnt; i += 256) {
        int r = row[base + i];
        int c = col[base + i];
        int b = r >> 7;
        int p = lscan[b] + atomicAdd(&lhist[b], 1);
        stage[p] = ((ull)(unsigned)c << 32) | (unsigned)r;
    }
    __syncthreads();

    for (int b = t; b < NBUCK; b += 256) {
        int c = lhist[b];
        gbase[b] = c ? atomicAdd(&bfill[b], c) : 0;
    }
    __syncthreads();

    for (int i = t; i < cnt; i += 256) {
        ull pk = stage[i];
        int b = ((int)(unsigned)(pk & 0xffffffffull)) >> 7;
        int dst = gbase[b] + (i - lscan[b]);
        ebuf[dst] = pk;
    }
}

// ---------------- CSR phase B: in-bucket sort + per-row degree/offset/dinv ----------------

__global__ __launch_bounds__(256) void k_bsort(const ull* __restrict__ ebuf,
                                               const int* __restrict__ bbase,
                                               int* __restrict__ off, int* __restrict__ cnt,
                                               float* __restrict__ dinv,
                                               int* __restrict__ scol) {
    __shared__ ull stage[BCAP];     // 32 KB
    __shared__ int lcol[BCAP];      // 16 KB
    __shared__ int lrc[128];
    __shared__ int lexcl[128];
    __shared__ int lfill[128];
    int b = blockIdx.x;
    int rowbase = b << 7;
    int segstart = bbase[b];
    int m = bbase[b + 1] - segstart;
    int t = threadIdx.x;

    if (t < 128) lrc[t] = 0;
    __syncthreads();
    for (int i = t; i < m; i += 256) {
        ull pk = ebuf[segstart + i];
        if (i < BCAP) stage[i] = pk;
        atomicAdd(&lrc[(int)(unsigned)(pk & 0xffffffffull) & 127], 1);
    }
    __syncthreads();
    if (t < 128) lexcl[t] = lrc[t];
    __syncthreads();
    for (int d = 1; d < 128; d <<= 1) {
        int xv = (t >= d && t < 128) ? lexcl[t - d] : 0;
        __syncthreads();
        if (t < 128) lexcl[t] += xv;
        __syncthreads();
    }
    if (t < 128) {
        int excl = lexcl[t] - lrc[t];
        lfill[t] = excl;
        int r = rowbase + t;
        if (r < N_NODES) {
            off[r] = segstart + excl;
            cnt[r] = lrc[t];
            dinv[r] = rsqrtf((float)lrc[t] + 1.0f);
        }
    }
    __syncthreads();
    for (int i = t; i < m; i += 256) {
        ull pk = (i < BCAP) ? stage[i] : ebuf[segstart + i];
        int r = (int)(unsigned)(pk & 0xffffffffull);
        int c = (int)(unsigned)(pk >> 32);
        int p = atomicAdd(&lfill[r & 127], 1);
        if (p < BCAP) lcol[p] = c;
        else scol[segstart + p] = c;
    }
    __syncthreads();
    int mm = m < BCAP ? m : BCAP;
    for (int i = t; i < mm; i += 256) scol[segstart + i] = lcol[i];
}

// ---------------- PaGNN masked-mean aggregation: wave/node, scalar ids, SGPR-base gather ----------------
// ids are wave-uniform -> s_load; per-edge vector work: 1 global_load + 2 fdot2 + 2 cmp/add.

__global__ __launch_bounds__(256) void k_agg(const __half* __restrict__ xh,
                                             const int* __restrict__ scol,
                                             const int* __restrict__ off, const int* __restrict__ cnt,
                                             uint* __restrict__ hb16) {
    int wv = threadIdx.x >> 6;
    int wid = blockIdx.x * 4 + wv;
    int l = threadIdx.x & 63;
    if (wid >= N_NODES) return;
    int swid = RFL(wid);
    int sstart = RFL(off[swid]);
    int slen = RFL(cnt[swid]);
    const uint* xu = (const uint*)xh;   // index: node*64 + l  (features 2l, 2l+1)

    float ax0 = 0.f, ay0 = 0.f, ax1 = 0.f, ay1 = 0.f;
    float ax2 = 0.f, ay2 = 0.f, ax3 = 0.f, ay3 = 0.f;
    int ix0 = 0, iy0 = 0, ix1 = 0, iy1 = 0;
    int ix2 = 0, iy2 = 0, ix3 = 0, iy3 = 0;

    int j = 0;
    for (; j + 8 <= slen; j += 8) {
        int c0 = RFL(scol[sstart + j + 0]);
        int c1 = RFL(scol[sstart + j + 1]);
        int c2 = RFL(scol[sstart + j + 2]);
        int c3 = RFL(scol[sstart + j + 3]);
        int c4 = RFL(scol[sstart + j + 4]);
        int c5 = RFL(scol[sstart + j + 5]);
        int c6 = RFL(scol[sstart + j + 6]);
        int c7 = RFL(scol[sstart + j + 7]);
        uint u0 = xu[(size_t)c0 * 64 + l];
        uint u1 = xu[(size_t)c1 * 64 + l];
        uint u2 = xu[(size_t)c2 * 64 + l];
        uint u3 = xu[(size_t)c3 * 64 + l];
        uint u4 = xu[(size_t)c4 * 64 + l];
        uint u5 = xu[(size_t)c5 * 64 + l];
        uint u6 = xu[(size_t)c6 * 64 + l];
        uint u7 = xu[(size_t)c7 * 64 + l];
        acc_xy(u0, ax0, ay0); cnt_xy(u0, ix0, iy0);
        acc_xy(u1, ax1, ay1); cnt_xy(u1, ix1, iy1);
        acc_xy(u2, ax2, ay2); cnt_xy(u2, ix2, iy2);
        acc_xy(u3, ax3, ay3); cnt_xy(u3, ix3, iy3);
        acc_xy(u4, ax0, ay0); cnt_xy(u4, ix0, iy0);
        acc_xy(u5, ax1, ay1); cnt_xy(u5, ix1, iy1);
        acc_xy(u6, ax2, ay2); cnt_xy(u6, ix2, iy2);
        acc_xy(u7, ax3, ay3); cnt_xy(u7, ix3, iy3);
    }
    for (; j + 4 <= slen; j += 4) {
        int c0 = RFL(scol[sstart + j + 0]);
        int c1 = RFL(scol[sstart + j + 1]);
        int c2 = RFL(scol[sstart + j + 2]);
        int c3 = RFL(scol[sstart + j + 3]);
        uint u0 = xu[(size_t)c0 * 64 + l];
        uint u1 = xu[(size_t)c1 * 64 + l];
        uint u2 = xu[(size_t)c2 * 64 + l];
        uint u3 = xu[(size_t)c3 * 64 + l];
        acc_xy(u0, ax0, ay0); cnt_xy(u0, ix0, iy0);
        acc_xy(u1, ax1, ay1); cnt_xy(u1, ix1, iy1);
        acc_xy(u2, ax2, ay2); cnt_xy(u2, ix2, iy2);
        acc_xy(u3, ax3, ay3); cnt_xy(u3, ix3, iy3);
    }
    for (; j < slen; j++) {
        int c0 = RFL(scol[sstart + j]);
        uint u0 = xu[(size_t)c0 * 64 + l];
        acc_xy(u0, ax0, ay0); cnt_xy(u0, ix0, iy0);
    }

    float ax = (ax0 + ax1) + (ax2 + ax3);
    float ay = (ay0 + ay1) + (ay2 + ay3);
    float dx = (float)((ix0 + ix1) + (ix2 + ix3));
    float dy = (float)((iy0 + iy1) + (iy2 + iy3));
    float hx = ax / fmaxf(dx, 1.0f);
    float hy = ay / fmaxf(dy, 1.0f);
    hb16[(size_t)wid * 64 + l] = (uint)f2bf(hx) | ((uint)f2bf(hy) << 16);
}

// ---------------- fused MLP (persistent MFMA): xws_h = fp16( dinv * relu(hn@W1+b1) @ W2 ) ----------------

#define MLP_TILES ((N_NODES + 63) / 64)   // 1563
#define MLP_GRID 512
#define LDW 136                            // padded row stride (bf16) -> 2-way banks, free

__global__ __launch_bounds__(256) void k_mlp(const uint* __restrict__ hb16,
                                             const float* __restrict__ W1,
                                             const float* __restrict__ b1,
                                             const float* __restrict__ W2,
                                             const float* __restrict__ dinv,
                                             __half* __restrict__ xws_h) {
    __shared__ ushort sW1T[128 * LDW];   // W1^T bf16: [n][k], 34 KB
    __shared__ ushort sW2T[48 * LDW];    // W2^T bf16: [n][k], cols 40..47 zero, 12.75 KB
    __shared__ ushort sA[64 * LDW];      // hn tile / then h tile, 17 KB
    __shared__ float sb1[128];
    int t = threadIdx.x;

    for (int i = t; i < 128 * 128; i += 256) {
        int k = i >> 7, nn = i & 127;
        sW1T[nn * LDW + k] = f2bf(W1[i]);
    }
    for (int i = t; i < 48 * LDW; i += 256) sW2T[i] = 0;
    if (t < 128) sb1[t] = b1[t];
    __syncthreads();
    for (int i = t; i < 128 * C_DIM; i += 256) {
        int k = i / C_DIM, nn = i - k * C_DIM;
        sW2T[nn * LDW + k] = f2bf(W2[i]);
    }

    int wv = t >> 6, l = t & 63;
    int lr = l & 15, quad = l >> 4;

    for (int tile = blockIdx.x; tile < MLP_TILES; tile += MLP_GRID) {
        int rowbase = tile * 64;
        __syncthreads();   // protect sA from previous iteration readers
        for (int i = t; i < 1024; i += 256) {
            int r = i >> 4, c = i & 15;     // c: uint4 index within row (16 B = 8 bf16)
            uint4 v = make_uint4(0, 0, 0, 0);
            if (rowbase + r < N_NODES)
                v = ((const uint4*)hb16)[(size_t)(rowbase + r) * 16 + c];
            *(uint4*)&sA[r * LDW + c * 8] = v;
        }
        __syncthreads();

        // ---- GEMM1: h = relu(hn @ W1 + b1), stay in this wave's 16 rows ----
        bf16x8 af[4];
#pragma unroll
        for (int kk = 0; kk < 4; kk++)
            af[kk] = *(const bf16x8*)&sA[(wv * 16 + lr) * LDW + kk * 32 + quad * 8];

        f32x4 acc[8];
#pragma unroll
        for (int ct = 0; ct < 8; ct++) {
            acc[ct] = (f32x4){0.f, 0.f, 0.f, 0.f};
#pragma unroll
            for (int kk = 0; kk < 4; kk++) {
                bf16x8 bf = *(const bf16x8*)&sW1T[(ct * 16 + lr) * LDW + kk * 32 + quad * 8];
                acc[ct] = __builtin_amdgcn_mfma_f32_16x16x32_bf16(af[kk], bf, acc[ct], 0, 0, 0);
            }
        }
#pragma unroll
        for (int ct = 0; ct < 8; ct++) {
            float bb = sb1[ct * 16 + lr];
#pragma unroll
            for (int r = 0; r < 4; r++) {
                float hv = fmaxf(acc[ct][r] + bb, 0.0f);
                sA[(wv * 16 + quad * 4 + r) * LDW + ct * 16 + lr] = f2bf(hv);
            }
        }
        // ---- GEMM2: xws = dinv * (h @ W2) ---- (same wave's rows: LDS in-order, no barrier)
        bf16x8 hf[4];
#pragma unroll
        for (int kk = 0; kk < 4; kk++)
            hf[kk] = *(const bf16x8*)&sA[(wv * 16 + lr) * LDW + kk * 32 + quad * 8];

        float dv[4];
#pragma unroll
        for (int r = 0; r < 4; r++) {
            int grow = rowbase + wv * 16 + quad * 4 + r;
            dv[r] = (grow < N_NODES) ? dinv[grow] : 0.0f;
        }
#pragma unroll
        for (int ct2 = 0; ct2 < 3; ct2++) {
            f32x4 acc2 = (f32x4){0.f, 0.f, 0.f, 0.f};
#pragma unroll
            for (int kk = 0; kk < 4; kk++) {
                bf16x8 bf = *(const bf16x8*)&sW2T[(ct2 * 16 + lr) * LDW + kk * 32 + quad * 8];
                acc2 = __builtin_amdgcn_mfma_f32_16x16x32_bf16(hf[kk], bf, acc2, 0, 0, 0);
            }
            int nn = ct2 * 16 + lr;
            if (nn < C_DIM) {
#pragma unroll
                for (int r = 0; r < 4; r++) {
                    int grow = rowbase + wv * 16 + quad * 4 + r;
                    if (grow < N_NODES)
                        xws_h[(size_t)grow * C_DIM + nn] = __float2half(acc2[r] * dv[r]);
                }
            }
        }
    }
}

// ---------------- GCN conv + bias + log_softmax: wave/node, scalar ids, 2 classes/lane fp16 ----------------

__global__ __launch_bounds__(256) void k_gcn(const __half* __restrict__ xws_h,
                                             const float* __restrict__ dinv,
                                             const int* __restrict__ scol,
                                             const int* __restrict__ off, const int* __restrict__ cnt,
                                             const float* __restrict__ b2,
                                             float* __restrict__ out) {
    int wv = threadIdx.x >> 6;
    int wid = blockIdx.x * 4 + wv;
    int l = threadIdx.x & 63;
    if (wid >= N_NODES) return;
    int swid = RFL(wid);
    int sstart = RFL(off[swid]);
    int slen = RFL(cnt[swid]);
    bool act = l < (C_DIM / 2);           // lanes 0..19 own classes 2l, 2l+1
    int ll = act ? l : 0;
    const uint* xp = (const uint*)xws_h;   // index: node*20 + ll

    float sx0 = 0.f, sy0 = 0.f, sx1 = 0.f, sy1 = 0.f;
    float sx2 = 0.f, sy2 = 0.f, sx3 = 0.f, sy3 = 0.f;
    int j = 0;
    for (; j + 8 <= slen; j += 8) {
        int c0 = RFL(scol[sstart + j + 0]);
        int c1 = RFL(scol[sstart + j + 1]);
        int c2 = RFL(scol[sstart + j + 2]);
        int c3 = RFL(scol[sstart + j + 3]);
        int c4 = RFL(scol[sstart + j + 4]);
        int c5 = RFL(scol[sstart + j + 5]);
        int c6 = RFL(scol[sstart + j + 6]);
        int c7 = RFL(scol[sstart + j + 7]);
        uint u0 = xp[(size_t)c0 * 20 + ll];
        uint u1 = xp[(size_t)c1 * 20 + ll];
        uint u2 = xp[(size_t)c2 * 20 + ll];
        uint u3 = xp[(size_t)c3 * 20 + ll];
        uint u4 = xp[(size_t)c4 * 20 + ll];
        uint u5 = xp[(size_t)c5 * 20 + ll];
        uint u6 = xp[(size_t)c6 * 20 + ll];
        uint u7 = xp[(size_t)c7 * 20 + ll];
        acc_xy(u0, sx0, sy0);
        acc_xy(u1, sx1, sy1);
        acc_xy(u2, sx2, sy2);
        acc_xy(u3, sx3, sy3);
        acc_xy(u4, sx0, sy0);
        acc_xy(u5, sx1, sy1);
        acc_xy(u6, sx2, sy2);
        acc_xy(u7, sx3, sy3);
    }
    for (; j + 4 <= slen; j += 4) {
        int c0 = RFL(scol[sstart + j + 0]);
        int c1 = RFL(scol[sstart + j + 1]);
        int c2 = RFL(scol[sstart + j + 2]);
        int c3 = RFL(scol[sstart + j + 3]);
        uint u0 = xp[(size_t)c0 * 20 + ll];
        uint u1 = xp[(size_t)c1 * 20 + ll];
        uint u2 = xp[(size_t)c2 * 20 + ll];
        uint u3 = xp[(size_t)c3 * 20 + ll];
        acc_xy(u0, sx0, sy0);
        acc_xy(u1, sx1, sy1);
        acc_xy(u2, sx2, sy2);
        acc_xy(u3, sx3, sy3);
    }
    for (; j < slen; j++) {
        int c0 = RFL(scol[sstart + j]);
        uint u0 = xp[(size_t)c0 * 20 + ll];
        acc_xy(u0, sx0, sy0);
    }

    float di = dinv[swid];
    uint us = xp[(size_t)swid * 20 + ll];
    float sx = (sx0 + sx1) + (sx2 + sx3);
    float sy = (sy0 + sy1) + (sy2 + sy3);
    acc_xy(us, sx, sy);
    float2 bb = act ? ((const float2*)b2)[ll] : make_float2(0.f, 0.f);
    float val0 = di * sx + bb.x;
    float val1 = di * sy + bb.y;

    float m = act ? fmaxf(val0, val1) : -1e30f;
#pragma unroll
    for (int o = 32; o > 0; o >>= 1) m = fmaxf(m, __shfl_xor(m, o, 64));
    float e = act ? (__expf(val0 - m) + __expf(val1 - m)) : 0.0f;
#pragma unroll
    for (int o = 32; o > 0; o >>= 1) e += __shfl_xor(e, o, 64);
    if (act) {
        float lse = m + __logf(e);
        float2 o2 = make_float2(val0 - lse, val1 - lse);
        ((float2*)out)[(size_t)wid * 20 + l] = o2;
    }
}

// ---------------- launch ----------------

extern "C" void kernel_launch(void* const* d_in, const int* in_sizes, int n_in,
                              void* d_out, int out_size, void* d_ws, size_t ws_size,
                              hipStream_t stream) {
    const float* x = (const float*)d_in[0];
    const int* mask = (const int*)d_in[1];
    const int* eidx = (const int*)d_in[2];
    const float* W1 = (const float*)d_in[3];
    const float* b1 = (const float*)d_in[4];
    const float* W2 = (const float*)d_in[5];
    const float* b2 = (const float*)d_in[6];
    float* out = (float*)d_out;

    const int* row = eidx;
    const int* col = eidx + N_EDGES;

    char* base = (char*)d_ws;
    size_t o = 0;
    auto alloc = [&](size_t bytes) {
        void* p = base + o;
        o = (o + bytes + 255) & ~(size_t)255;
        return p;
    };
    int* cnt = (int*)alloc(N_NODES * 4);
    int* off = (int*)alloc(N_NODES * 4);
    float* dinv = (float*)alloc(N_NODES * 4);
    int* bcnt = (int*)alloc(NBUCK * 4);
    int* bbase = (int*)alloc((NBUCK + 1) * 4);
    int* bfill = (int*)alloc(NBUCK * 4);
    int* scol = (int*)alloc(N_EDGES * 4);
    __half* xh = (__half*)alloc((size_t)N_NODES * F_DIM * 2);
    uint* hb16 = (uint*)alloc((size_t)N_NODES * F_DIM * 2);   // hn as bf16 (uint-packed pairs)
    __half* xws_h = (__half*)alloc((size_t)N_NODES * C_DIM * 2);
    (void)ws_size;

    ull* ebuf = (ull*)hb16;   // alias: ebuf (12.8 MB) dead before k_agg writes hb16 (25.6 MB)

    hipMemsetAsync(bcnt, 0, NBUCK * 4, stream);

    k_prep<<<NBLK_BUCKET + G_NODE, 256, 0, stream>>>(row, mask, x, bcnt, xh);
    k_bscan<<<1, 256, 0, stream>>>(bcnt, bbase, bfill);
    k_bucket<<<NBLK_BUCKET, 256, 0, stream>>>(row, col, bfill, ebuf);
    k_bsort<<<NBUCK, 256, 0, stream>>>(ebuf, bbase, off, cnt, dinv, scol);
    k_agg<<<G_NODE, 256, 0, stream>>>(xh, scol, off, cnt, hb16);
    k_mlp<<<MLP_GRID, 256, 0, stream>>>(hb16, W1, b1, W2, dinv, xws_h);
    k_gcn<<<G_NODE, 256, 0, stream>>>(xws_h, dinv, scol, off, cnt, b2, out);
}